// Round 10
// baseline (119.303 us; speedup 1.0000x reference)
//
#include <hip/hip_runtime.h>

// MultiHeadAttentionForViTDiscriminator: B=4, C=1024, D=1024, H=16, DH=64
// R10: GEMM arithmetic-intensity fix: 128x128 block, 64x64 wave tile (16 MFMA32
//      per 16 LDS reads = 32 FLOP/LDS-byte, 4x R9) -- the GEMM was LDS-BW-bound.
//      All-f16 staging restored (cvt_all); fused-f32 staging abandoned (2x LDS
//      bytes, net loss both attempts). Swizzled gload_lds source + XOR frag
//      reads kept from R9 (verified). attn = R9-proven, untouched.
// Workspace (48 MB):
//   [0,8M)  W16 (Wq,Wk,Wv,Wp f16)
//   [8,32M) X16: Xq16,Xk16,Xv16; Xq16 slot -> vTb after qk-gemm,
//           Xk16 slot -> attnout after vT-gemm
//   [32,40M) qb (pre-scaled by -2*C2)  [40,48M) kb
//   norms q2c2/k2c2 (2 x 256KB f32) live in d_out's head (dead before final GEMM).

typedef _Float16 f16;
typedef __attribute__((ext_vector_type(2))) _Float16 f16x2;
typedef __attribute__((ext_vector_type(8))) _Float16 f16x8;
typedef __attribute__((ext_vector_type(4))) float f32x4;
typedef __attribute__((ext_vector_type(16))) float f32x16;

#define MFMA16(a, b, c) __builtin_amdgcn_mfma_f32_16x16x32_f16((a), (b), (c), 0, 0, 0)
#define MFMA32(a, b, c) __builtin_amdgcn_mfma_f32_32x32x16_f16((a), (b), (c), 0, 0, 0)

constexpr double LOG2E = 1.4426950408889634;
constexpr double C2d = 0.015625 * LOG2E * LOG2E;  // (DH^-0.5 * log2e)^2

#if __has_builtin(__builtin_amdgcn_exp2f)
#define EXP2F(x) __builtin_amdgcn_exp2f(x)
#else
#define EXP2F(x) exp2f(x)
#endif
#if __has_builtin(__builtin_amdgcn_sqrtf)
#define SQRTF(x) __builtin_amdgcn_sqrtf(x)
#else
#define SQRTF(x) sqrtf(x)
#endif

// Async global->LDS, 16B per lane (dest = wave-uniform base + lane*16).
__device__ __forceinline__ void stage16(const void* g, void* lds_base_uniform) {
#if __has_builtin(__builtin_amdgcn_global_load_lds)
    __builtin_amdgcn_global_load_lds((const __attribute__((address_space(1))) void*)g,
                                     (__attribute__((address_space(3))) void*)lds_base_uniform,
                                     16, 0, 0);
#else
    const int lane = threadIdx.x & 63;
    *(f16x8*)((f16*)lds_base_uniform + lane * 8) = *(const f16x8*)g;
#endif
}

__device__ __forceinline__ f16x8 cvt8v(f32x4 a, f32x4 b) {
    f16x8 o;
    o[0] = (f16)a[0]; o[1] = (f16)a[1]; o[2] = (f16)a[2]; o[3] = (f16)a[3];
    o[4] = (f16)b[0]; o[5] = (f16)b[1]; o[6] = (f16)b[2]; o[7] = (f16)b[3];
    return o;
}

// One conversion kernel for all fp32->f16 inputs. 8192 blocks x 2048 elems = 16M.
__global__ __launch_bounds__(256) void cvt_all(const float* __restrict__ Xq,
                                               const float* __restrict__ Xk,
                                               const float* __restrict__ Xv,
                                               const float* __restrict__ Wq,
                                               const float* __restrict__ Wk,
                                               const float* __restrict__ Wv,
                                               const float* __restrict__ Wp,
                                               f16* __restrict__ W16,
                                               f16* __restrict__ X16) {
    const size_t idx = (size_t)blockIdx.x * 2048 + threadIdx.x * 8;
    const size_t M4 = 4ull << 20, M1 = 1ull << 20;
    const float* s;
    f16* d;
    if (idx < 3 * M4) {  // X region (12M)
        if (idx < M4) s = Xq + idx;
        else if (idx < 2 * M4) s = Xk + (idx - M4);
        else s = Xv + (idx - 2 * M4);
        d = X16 + idx;
    } else {  // W region (4M)
        size_t wi = idx - 3 * M4;
        if (wi < M1) s = Wq + wi;
        else if (wi < 2 * M1) s = Wk + (wi - M1);
        else if (wi < 3 * M1) s = Wv + (wi - 2 * M1);
        else s = Wp + (wi - 3 * M1);
        d = W16 + wi;
    }
    f32x4 a = *(const f32x4*)s;
    f32x4 b = *(const f32x4*)(s + 4);
    *(f16x8*)d = cvt8v(a, b);
}

// C[M,N] = (A[M,K] * B[N,K]^T) * osc.  BM=128 BN=128 BK=64; 4 waves (2x2),
// wave tile 64x64 (acc 2x2 f32x16), MFMA 32x32x16.  XOR-swizzled LDS
// (pre-swizzled gload_lds source granule g ^= row&7; same XOR on frag read).
// MODE 0: qk fused (z=0 q / z=1 k), f16 out * osc, NORMS epilogue.
// MODE 1: vT (f16 out).   MODE 2: final (f32 out + bias).
template <int MODE>
__global__ __launch_bounds__(256, 2) void gemm(const f16* __restrict__ A,
                                               const f16* __restrict__ B,
                                               f16* __restrict__ Co,
                                               float* __restrict__ Cf,
                                               const float* __restrict__ bias,
                                               float* __restrict__ nrm,
                                               float osc0, float osc1,
                                               float ns0, float ns1,
                                               int M, int N, int K) {
    constexpr bool NORMS = (MODE == 0);
    constexpr bool F32OUT = (MODE == 2);
    __shared__ __attribute__((aligned(16))) f16 As[128 * 64];
    __shared__ __attribute__((aligned(16))) f16 Bs[128 * 64];
    const int tid = threadIdx.x;
    const int lane = tid & 63;
    const int w = tid >> 6;
    const int l31 = lane & 31, l5 = lane >> 5;
    const int z = blockIdx.z;
    const f16* Ap = (MODE == 0) ? A + (size_t)z * (4u << 20) : A;
    const f16* Bp = (MODE == 0) ? B + (size_t)z * (1u << 20) : B;
    f16* Cop = (MODE == 0) ? Co + (size_t)z * (4u << 20) : Co;
    float* nrmp = NORMS ? nrm + (size_t)z * 65536 : nullptr;
    const float osc = z ? osc1 : osc0;
    const float nscale = z ? ns1 : ns0;
    const int wr = (w >> 1) * 64, wc = (w & 1) * 64;
    // bijective XCD swizzle (nwg multiple of 8)
    const int nwg = gridDim.x * gridDim.y;
    const int f = blockIdx.y * gridDim.x + blockIdx.x;
    const int g = (f & 7) * (nwg >> 3) + (f >> 3);
    const int row0 = (g / gridDim.x) * 128;
    const int col0 = (g % gridDim.x) * 128;

    f32x16 acc[2][2] = {};

    for (int kt = 0; kt < K; kt += 64) {
        __syncthreads();
        // stage A,B: 4 gloads each per wave; source granule pre-swizzled
#pragma unroll
        for (int t = 0; t < 4; ++t) {
            const int rb = w * 32 + t * 8;
            const int rr = rb + (lane >> 3);
            const int gs = (lane & 7) ^ (rr & 7);
            stage16(&Ap[(size_t)(row0 + rr) * K + kt + gs * 8], &As[rb * 64]);
            stage16(&Bp[(size_t)(col0 + rr) * K + kt + gs * 8], &Bs[rb * 64]);
        }
        __syncthreads();
#pragma unroll
        for (int ks = 0; ks < 4; ++ks) {  // K=64 -> 4 x K16
            const int gq = ks * 2 + l5;   // logical granule of this lane's 8 elems
            f16x8 af[2], bf[2];
#pragma unroll
            for (int mr = 0; mr < 2; ++mr)
                af[mr] = *(const f16x8*)&As[(wr + mr * 32 + l31) * 64 + ((gq ^ (l31 & 7)) * 8)];
#pragma unroll
            for (int n2 = 0; n2 < 2; ++n2)
                bf[n2] = *(const f16x8*)&Bs[(wc + n2 * 32 + l31) * 64 + ((gq ^ (l31 & 7)) * 8)];
#pragma unroll
            for (int mr = 0; mr < 2; ++mr)
#pragma unroll
                for (int n2 = 0; n2 < 2; ++n2) acc[mr][n2] = MFMA32(af[mr], bf[n2], acc[mr][n2]);
        }
    }

    // D layout (R9-verified): col = wc + n2*32 + l31, row = wr + mr*32 + (j&3)+8*(j>>2)+4*l5
    const int cc0 = col0 + wc + l31;
    const int cc1 = col0 + wc + 32 + l31;
    const int hh = (col0 + wc) >> 6;  // one head per wave column (64 cols)
#pragma unroll
    for (int mr = 0; mr < 2; ++mr)
#pragma unroll
        for (int j = 0; j < 16; ++j) {
            const int rr = row0 + wr + mr * 32 + (j & 3) + 8 * (j >> 2) + 4 * l5;
            if (F32OUT) {
                Cf[(size_t)rr * N + cc0] = acc[mr][0][j] + bias[cc0];
                Cf[(size_t)rr * N + cc1] = acc[mr][1][j] + bias[cc1];
            } else {
                const f16 h0 = (f16)(acc[mr][0][j] * osc);
                const f16 h1 = (f16)(acc[mr][1][j] * osc);
                if (NORMS) {
                    float v0 = (float)h0, v1 = (float)h1;
                    float s = v0 * v0 + v1 * v1;
                    s += __shfl_xor(s, 1);
                    s += __shfl_xor(s, 2);
                    s += __shfl_xor(s, 4);
                    s += __shfl_xor(s, 8);
                    s += __shfl_xor(s, 16);
                    if (l31 == 0)
                        nrmp[(size_t)((rr >> 10) * 16 + hh) * 1024 + (rr & 1023)] = s * nscale;
                }
                Cop[(size_t)rr * N + cc0] = h0;
                Cop[(size_t)rr * N + cc1] = h1;
            }
        }
}

// Distance attention (R9-proven, byte-identical). grid (8,64).
__global__ __launch_bounds__(256, 2) void attn(const f16* __restrict__ qs,
                                               const f16* __restrict__ kb,
                                               const f16* __restrict__ vT,
                                               const float* __restrict__ q2c2,
                                               const float* __restrict__ k2c2,
                                               f16* __restrict__ out) {
    __shared__ __attribute__((aligned(16))) f16 Ks[128 * 64];  // permuted slots + XOR swizzle
    __shared__ __attribute__((aligned(16))) f16 Vs[64 * 128];  // XOR-swizzled
    __shared__ float k2tile[128];                              // linear (keyed by true k)
    const int tid = threadIdx.x;
    const int lane = tid & 63;
    const int w = tid >> 6;
    const int l15 = lane & 15, l4 = lane >> 4;
    const int fid = blockIdx.y * 8 + blockIdx.x;
    const int qt = (fid >> 3) & 7;
    const int bh = (fid & 7) * 8 + (fid >> 6);
    const int b = bh >> 4, h = bh & 15;
    const int wq = w * 32;
    const int hcol = h * 64;
    const int qrow0 = b * 1024 + qt * 128;
    const f16* vTh = vT + (size_t)hcol * 4096 + b * 1024;  // vT[d=1024][tok=4096]

    const int sr = tid >> 3, sc0 = (tid & 7) * 8;   // K staging (keys sr+i*32)
    const int vr = tid >> 4, vc0 = (tid & 15) * 8;  // V staging (rows vr+j*16)
    const int vsw = (vr & 7) << 3;
    const int fsw = (l15 & 7) << 3;                 // fragment-read swizzle

    f16x8 bq[2][2];
#pragma unroll
    for (int m = 0; m < 2; ++m)
#pragma unroll
        for (int ks = 0; ks < 2; ++ks)
            bq[m][ks] = *(const f16x8*)&qs[(size_t)(qrow0 + wq + m * 16 + l15) * 1024 + hcol + ks * 32 + l4 * 8];
    float q2m[2];
#pragma unroll
    for (int m = 0; m < 2; ++m) q2m[m] = q2c2[(size_t)bh * 1024 + qt * 128 + wq + m * 16 + l15];

    f32x4 accv[2][4] = {};
    f32x4 dacc[2] = {};
    const f16 one = (f16)1.f;
    const f16x8 ones8 = {one, one, one, one, one, one, one, one};

    f16x8 kreg[4], vreg[4];
    float k2reg = 0.f;
#define ISSUE_LOADS(KT)                                                                                      \
    {                                                                                                        \
        _Pragma("unroll") for (int i = 0; i < 4; ++i)                                                        \
            kreg[i] = *(const f16x8*)&kb[(size_t)(b * 1024 + (KT) * 128 + sr + i * 32) * 1024 + hcol + sc0]; \
        _Pragma("unroll") for (int j = 0; j < 4; ++j)                                                        \
            vreg[j] = *(const f16x8*)&vTh[(size_t)(vr + j * 16) * 4096 + (KT) * 128 + vc0];                  \
        k2reg = (tid < 128) ? k2c2[(size_t)bh * 1024 + (KT) * 128 + tid] : 0.f;                              \
    }

    ISSUE_LOADS(0)

    for (int kt = 0; kt < 8; ++kt) {
        __syncthreads();
#pragma unroll
        for (int i = 0; i < 4; ++i) {
            const int kap = sr + i * 32;
            const int s = ((kap >> 5) & 3) * 32 + ((kap >> 2) & 1) * 16 + ((kap >> 3) & 3) * 4 + (kap & 3);
            *(f16x8*)&Ks[s * 64 + (sc0 ^ ((s & 7) << 3))] = kreg[i];
        }
#pragma unroll
        for (int j = 0; j < 4; ++j) *(f16x8*)&Vs[(vr + j * 16) * 128 + (vc0 ^ vsw)] = vreg[j];
        if (tid < 128) k2tile[tid] = k2reg;
        __syncthreads();
        if (kt < 7) ISSUE_LOADS(kt + 1)

#pragma unroll
        for (int kk = 0; kk < 4; ++kk) {
            unsigned um[2][4];
#pragma unroll
            for (int half = 0; half < 2; ++half) {
                const int n = kk * 2 + half;
                f16x8 kf0 = *(const f16x8*)&Ks[(n * 16 + l15) * 64 + ((l4 * 8) ^ fsw)];
                f16x8 kf1 = *(const f16x8*)&Ks[(n * 16 + l15) * 64 + ((32 + l4 * 8) ^ fsw)];
                f32x4 k2q = *(const f32x4*)&k2tile[kk * 32 + l4 * 8 + half * 4];
#pragma unroll
                for (int m = 0; m < 2; ++m) {
                    f32x4 c0;
#pragma unroll
                    for (int r = 0; r < 4; ++r) c0[r] = q2m[m] + k2q[r];
                    f32x4 st = MFMA16(kf0, bq[m][0], c0);
                    st = MFMA16(kf1, bq[m][1], st);
                    float p0 = EXP2F(SQRTF(fmaxf(st[0], 0.f)));
                    float p1 = EXP2F(SQRTF(fmaxf(st[1], 0.f)));
                    float p2 = EXP2F(SQRTF(fmaxf(st[2], 0.f)));
                    float p3 = EXP2F(SQRTF(fmaxf(st[3], 0.f)));
                    f16x2 lo = {(f16)p0, (f16)p1};
                    f16x2 hi = {(f16)p2, (f16)p3};
                    um[m][half * 2] = __builtin_bit_cast(unsigned, lo);
                    um[m][half * 2 + 1] = __builtin_bit_cast(unsigned, hi);
                }
            }
            f16x8 ap[2];
#pragma unroll
            for (int m = 0; m < 2; ++m) {
                uint4 u = {um[m][0], um[m][1], um[m][2], um[m][3]};
                ap[m] = __builtin_bit_cast(f16x8, u);
            }
#pragma unroll
            for (int m = 0; m < 2; ++m) dacc[m] = MFMA16(ap[m], ones8, dacc[m]);
#pragma unroll
            for (int n2 = 0; n2 < 4; ++n2) {
                f16x8 bv = *(const f16x8*)&Vs[(n2 * 16 + l15) * 128 + ((kk * 32 + l4 * 8) ^ fsw)];
#pragma unroll
                for (int m = 0; m < 2; ++m) accv[m][n2] = MFMA16(ap[m], bv, accv[m][n2]);
            }
        }
    }

#pragma unroll
    for (int m = 0; m < 2; ++m)
#pragma unroll
        for (int r = 0; r < 4; ++r) {
            const float rd = 1.0f / dacc[m][r];
#pragma unroll
            for (int n2 = 0; n2 < 4; ++n2)
                out[(size_t)(qrow0 + wq + m * 16 + l4 * 4 + r) * 1024 + hcol + n2 * 16 + l15] =
                    (f16)(accv[m][n2][r] * rd);
        }
}

extern "C" void kernel_launch(void* const* d_in, const int* in_sizes, int n_in,
                              void* d_out, int out_size, void* d_ws, size_t ws_size,
                              hipStream_t stream) {
    const float* Xq = (const float*)d_in[0];
    const float* Xk = (const float*)d_in[1];
    const float* Xv = (const float*)d_in[2];
    const float* Wq = (const float*)d_in[3];
    const float* Wk = (const float*)d_in[4];
    const float* Wv = (const float*)d_in[5];
    const float* Wp = (const float*)d_in[6];
    const float* bp = (const float*)d_in[7];
    float* out = (float*)d_out;

    char* ws = (char*)d_ws;
    f16* W16 = (f16*)(ws);                      // 4M f16
    f16* X16 = (f16*)(ws + (8ull << 20));       // Xq16|Xk16|Xv16 (4M f16 each)
    f16* vTb = (f16*)(ws + (8ull << 20));       // overlays Xq16 (dead after qk-gemm)
    f16* attnout = (f16*)(ws + (16ull << 20));  // overlays Xk16 (dead after vT-gemm)
    f16* Xv16 = (f16*)(ws + (24ull << 20));
    f16* qb = (f16*)(ws + (32ull << 20));       // qk out base (z-stride 4M f16)
    f16* kb = (f16*)(ws + (40ull << 20));
    // norms scratch in d_out head; written each launch before use, overwritten by final GEMM
    float* q2c2 = out;
    float* k2c2 = out + 65536;

    const float qsc = (float)(-2.0 * C2d);
    const float ns_q = (float)(1.0 / (4.0 * C2d));  // (q*-2C2)^2 * ns_q = C2*q^2
    const float ns_k = (float)C2d;

    cvt_all<<<8192, 256, 0, stream>>>(Xq, Xk, Xv, Wq, Wk, Wv, Wp, W16, X16);

    // fused q+k projection (z=0: q with -2*C2 prescale, z=1: k), norms in epilogue
    gemm<0><<<dim3(8, 32, 2), 256, 0, stream>>>(
        X16, W16, qb, nullptr, nullptr, q2c2, qsc, 1.0f, ns_q, ns_k, 4096, 1024, 1024);

    // vT = Wv16 * Xv^T : [1024 d][4096 tok]
    gemm<1><<<dim3(32, 8), 256, 0, stream>>>(
        W16 + 2 * (1u << 20), Xv16, vTb, nullptr, nullptr, nullptr,
        1.0f, 1.0f, 0.f, 0.f, 1024, 4096, 1024);

    attn<<<dim3(8, 64), 256, 0, stream>>>(qb, kb, vTb, q2c2, k2c2, attnout);

    gemm<2><<<dim3(8, 32), 256, 0, stream>>>(
        attnout, W16 + 3 * (1u << 20), nullptr, out, bp, nullptr,
        1.0f, 1.0f, 0.f, 0.f, 4096, 1024, 1024);
}

// Round 11
// 113.262 us; speedup vs baseline: 1.0533x; 1.0533x over previous
//
#include <hip/hip_runtime.h>

// MultiHeadAttentionForViTDiscriminator: B=4, C=1024, D=1024, H=16, DH=64
// R11: machine-fill round. (1) attn: 512 threads, 2 K-groups (waves 0-3 keys
//      0-511, waves 4-7 keys 512-1023), LDS partial-merge epilogue -> 16
//      waves/CU (2x TLP); setprio around PV MFMAs. (2) qk-GEMM + vT-GEMM fused
//      into one 768-block launch (vT was 1 block/CU half-idle). (3) final GEMM
//      64x128 tiles -> 512 blocks (2/CU). GEMM inner loop = R10-verified.
// Workspace (64 MB):
//   [0,8M) W16  [8,32M) X16 (Xq|Xk|Xv f16)  [32,40M) qb  [40,48M) kb
//   [48,56M) vTb  [56,64M) attnout
//   norms q2c2/k2c2 (2 x 256KB f32) live in d_out's head (dead before final GEMM).

typedef _Float16 f16;
typedef __attribute__((ext_vector_type(2))) _Float16 f16x2;
typedef __attribute__((ext_vector_type(8))) _Float16 f16x8;
typedef __attribute__((ext_vector_type(4))) float f32x4;
typedef __attribute__((ext_vector_type(16))) float f32x16;

#define MFMA16(a, b, c) __builtin_amdgcn_mfma_f32_16x16x32_f16((a), (b), (c), 0, 0, 0)
#define MFMA32(a, b, c) __builtin_amdgcn_mfma_f32_32x32x16_f16((a), (b), (c), 0, 0, 0)

constexpr double LOG2E = 1.4426950408889634;
constexpr double C2d = 0.015625 * LOG2E * LOG2E;  // (DH^-0.5 * log2e)^2

#if __has_builtin(__builtin_amdgcn_exp2f)
#define EXP2F(x) __builtin_amdgcn_exp2f(x)
#else
#define EXP2F(x) exp2f(x)
#endif
#if __has_builtin(__builtin_amdgcn_sqrtf)
#define SQRTF(x) __builtin_amdgcn_sqrtf(x)
#else
#define SQRTF(x) sqrtf(x)
#endif

__device__ __forceinline__ void stage16(const void* g, void* lds_base_uniform) {
#if __has_builtin(__builtin_amdgcn_global_load_lds)
    __builtin_amdgcn_global_load_lds((const __attribute__((address_space(1))) void*)g,
                                     (__attribute__((address_space(3))) void*)lds_base_uniform,
                                     16, 0, 0);
#else
    const int lane = threadIdx.x & 63;
    *(f16x8*)((f16*)lds_base_uniform + lane * 8) = *(const f16x8*)g;
#endif
}

__device__ __forceinline__ f16x8 cvt8v(f32x4 a, f32x4 b) {
    f16x8 o;
    o[0] = (f16)a[0]; o[1] = (f16)a[1]; o[2] = (f16)a[2]; o[3] = (f16)a[3];
    o[4] = (f16)b[0]; o[5] = (f16)b[1]; o[6] = (f16)b[2]; o[7] = (f16)b[3];
    return o;
}

// One conversion kernel for all fp32->f16 inputs. 8192 blocks x 2048 elems = 16M.
__global__ __launch_bounds__(256) void cvt_all(const float* __restrict__ Xq,
                                               const float* __restrict__ Xk,
                                               const float* __restrict__ Xv,
                                               const float* __restrict__ Wq,
                                               const float* __restrict__ Wk,
                                               const float* __restrict__ Wv,
                                               const float* __restrict__ Wp,
                                               f16* __restrict__ W16,
                                               f16* __restrict__ X16) {
    const size_t idx = (size_t)blockIdx.x * 2048 + threadIdx.x * 8;
    const size_t M4 = 4ull << 20, M1 = 1ull << 20;
    const float* s;
    f16* d;
    if (idx < 3 * M4) {
        if (idx < M4) s = Xq + idx;
        else if (idx < 2 * M4) s = Xk + (idx - M4);
        else s = Xv + (idx - 2 * M4);
        d = X16 + idx;
    } else {
        size_t wi = idx - 3 * M4;
        if (wi < M1) s = Wq + wi;
        else if (wi < 2 * M1) s = Wk + (wi - M1);
        else if (wi < 3 * M1) s = Wv + (wi - 2 * M1);
        else s = Wp + (wi - 3 * M1);
        d = W16 + wi;
    }
    f32x4 a = *(const f32x4*)s;
    f32x4 b = *(const f32x4*)(s + 4);
    *(f16x8*)d = cvt8v(a, b);
}

// 128x128 GEMM body (R10-verified): BK=64, 4 waves (2x2), 64x64 wave tile,
// MFMA32, XOR-swizzled LDS via pre-swizzled gload_lds source.
template <bool NORMS, bool F32OUT>
__device__ __forceinline__ void gemm128(f16* As, f16* Bs,
                                        const f16* __restrict__ Ap,
                                        const f16* __restrict__ Bp,
                                        f16* __restrict__ Cop,
                                        float* __restrict__ Cf,
                                        const float* __restrict__ bias,
                                        float* __restrict__ nrmp,
                                        float osc, float nscale,
                                        int row0, int col0, int N, int K) {
    const int tid = threadIdx.x;
    const int lane = tid & 63;
    const int w = tid >> 6;
    const int l31 = lane & 31, l5 = lane >> 5;
    const int wr = (w >> 1) * 64, wc = (w & 1) * 64;

    f32x16 acc[2][2] = {};

    for (int kt = 0; kt < K; kt += 64) {
        __syncthreads();
#pragma unroll
        for (int t = 0; t < 4; ++t) {
            const int rb = w * 32 + t * 8;
            const int rr = rb + (lane >> 3);
            const int gs = (lane & 7) ^ (rr & 7);
            stage16(&Ap[(size_t)(row0 + rr) * K + kt + gs * 8], &As[rb * 64]);
            stage16(&Bp[(size_t)(col0 + rr) * K + kt + gs * 8], &Bs[rb * 64]);
        }
        __syncthreads();
#pragma unroll
        for (int ks = 0; ks < 4; ++ks) {
            const int gq = ks * 2 + l5;
            f16x8 af[2], bf[2];
#pragma unroll
            for (int mr = 0; mr < 2; ++mr)
                af[mr] = *(const f16x8*)&As[(wr + mr * 32 + l31) * 64 + ((gq ^ (l31 & 7)) * 8)];
#pragma unroll
            for (int n2 = 0; n2 < 2; ++n2)
                bf[n2] = *(const f16x8*)&Bs[(wc + n2 * 32 + l31) * 64 + ((gq ^ (l31 & 7)) * 8)];
#pragma unroll
            for (int mr = 0; mr < 2; ++mr)
#pragma unroll
                for (int n2 = 0; n2 < 2; ++n2) acc[mr][n2] = MFMA32(af[mr], bf[n2], acc[mr][n2]);
        }
    }

    const int cc0 = col0 + wc + l31;
    const int cc1 = col0 + wc + 32 + l31;
    const int hh = (col0 + wc) >> 6;
#pragma unroll
    for (int mr = 0; mr < 2; ++mr)
#pragma unroll
        for (int j = 0; j < 16; ++j) {
            const int rr = row0 + wr + mr * 32 + (j & 3) + 8 * (j >> 2) + 4 * l5;
            if (F32OUT) {
                Cf[(size_t)rr * N + cc0] = acc[mr][0][j] + bias[cc0];
                Cf[(size_t)rr * N + cc1] = acc[mr][1][j] + bias[cc1];
            } else {
                const f16 h0 = (f16)(acc[mr][0][j] * osc);
                const f16 h1 = (f16)(acc[mr][1][j] * osc);
                if (NORMS) {
                    float v0 = (float)h0, v1 = (float)h1;
                    float s = v0 * v0 + v1 * v1;
                    s += __shfl_xor(s, 1);
                    s += __shfl_xor(s, 2);
                    s += __shfl_xor(s, 4);
                    s += __shfl_xor(s, 8);
                    s += __shfl_xor(s, 16);
                    if (l31 == 0)
                        nrmp[(size_t)((rr >> 10) * 16 + hh) * 1024 + (rr & 1023)] = s * nscale;
                }
                Cop[(size_t)rr * N + cc0] = h0;
                Cop[(size_t)rr * N + cc1] = h1;
            }
        }
}

// Fused qk + vT launch: bid<512 -> qk (z=bid>>8); bid>=512 -> vT.
__global__ __launch_bounds__(256, 2) void gemm_qkv(const f16* __restrict__ X16,
                                                   const f16* __restrict__ W16,
                                                   f16* __restrict__ qb_base,
                                                   f16* __restrict__ vTb,
                                                   float* __restrict__ nrm,
                                                   float qsc, float ns_q, float ns_k) {
    __shared__ __attribute__((aligned(16))) f16 As[128 * 64];
    __shared__ __attribute__((aligned(16))) f16 Bs[128 * 64];
    const int bid = blockIdx.x;
    if (bid < 512) {
        const int z = bid >> 8;
        const int f = bid & 255;
        const int g = (f & 7) * 32 + (f >> 3);
        const int row0 = (g >> 3) * 128, col0 = (g & 7) * 128;
        gemm128<true, false>(As, Bs,
                             X16 + (size_t)z * (4u << 20), W16 + (size_t)z * (1u << 20),
                             qb_base + (size_t)z * (4u << 20), nullptr, nullptr,
                             nrm + (size_t)z * 65536,
                             z ? 1.0f : qsc, z ? ns_k : ns_q, row0, col0, 1024, 1024);
    } else {
        const int f = bid - 512;
        const int g = (f & 7) * 32 + (f >> 3);
        const int row0 = (g >> 5) * 128, col0 = (g & 31) * 128;
        gemm128<false, false>(As, Bs,
                              W16 + 2 * (1u << 20), X16 + 2 * (4u << 20),
                              vTb, nullptr, nullptr, nullptr,
                              1.0f, 0.f, row0, col0, 4096, 1024);
    }
}

// Final projection: 64x128 tiles, 512 blocks (2/CU). f32 out + bias.
__global__ __launch_bounds__(256, 2) void gemm_fin(const f16* __restrict__ A,
                                                   const f16* __restrict__ B,
                                                   float* __restrict__ Cf,
                                                   const float* __restrict__ bias) {
    __shared__ __attribute__((aligned(16))) f16 As[64 * 64];
    __shared__ __attribute__((aligned(16))) f16 Bs[128 * 64];
    const int tid = threadIdx.x;
    const int lane = tid & 63;
    const int w = tid >> 6;
    const int l31 = lane & 31, l5 = lane >> 5;
    const int wr = (w & 1) * 32, wc = (w >> 1) * 64;
    const int f = blockIdx.x;
    const int g = (f & 7) * 64 + (f >> 3);
    const int row0 = (g >> 3) * 64, col0 = (g & 7) * 128;
    const int K = 1024, N = 1024;

    f32x16 acc[2] = {};

    for (int kt = 0; kt < K; kt += 64) {
        __syncthreads();
#pragma unroll
        for (int t = 0; t < 2; ++t) {  // A: 64 rows
            const int rb = w * 16 + t * 8;
            const int rr = rb + (lane >> 3);
            const int gs = (lane & 7) ^ (rr & 7);
            stage16(&A[(size_t)(row0 + rr) * K + kt + gs * 8], &As[rb * 64]);
        }
#pragma unroll
        for (int t = 0; t < 4; ++t) {  // B: 128 rows
            const int rb = w * 32 + t * 8;
            const int rr = rb + (lane >> 3);
            const int gs = (lane & 7) ^ (rr & 7);
            stage16(&B[(size_t)(col0 + rr) * K + kt + gs * 8], &Bs[rb * 64]);
        }
        __syncthreads();
#pragma unroll
        for (int ks = 0; ks < 4; ++ks) {
            const int gq = ks * 2 + l5;
            f16x8 af = *(const f16x8*)&As[(wr + l31) * 64 + ((gq ^ (l31 & 7)) * 8)];
#pragma unroll
            for (int n2 = 0; n2 < 2; ++n2) {
                f16x8 bf = *(const f16x8*)&Bs[(wc + n2 * 32 + l31) * 64 + ((gq ^ (l31 & 7)) * 8)];
                acc[n2] = MFMA32(af, bf, acc[n2]);
            }
        }
    }

    const int cc0 = col0 + wc + l31;
    const int cc1 = col0 + wc + 32 + l31;
#pragma unroll
    for (int j = 0; j < 16; ++j) {
        const int rr = row0 + wr + (j & 3) + 8 * (j >> 2) + 4 * l5;
        Cf[(size_t)rr * N + cc0] = acc[0][j] + bias[cc0];
        Cf[(size_t)rr * N + cc1] = acc[1][j] + bias[cc1];
    }
}

// Distance attention: 512 threads, 2 K-groups (grp 0: keys 0-511, grp 1: 512-1023),
// per-group Ks/Vs/k2, shared barriers (same trip count), LDS partial merge.
// Inner compute per wave = R10-proven code. setprio(1) around PV MFMA cluster.
__global__ __launch_bounds__(512, 4) void attn(const f16* __restrict__ qs,
                                               const f16* __restrict__ kb,
                                               const f16* __restrict__ vT,
                                               const float* __restrict__ q2c2,
                                               const float* __restrict__ k2c2,
                                               f16* __restrict__ out) {
    __shared__ __attribute__((aligned(16))) char smem[67 * 1024];
    f16* KsA = (f16*)smem;                 // [2][128*64] = 32 KB
    f16* VsA = (f16*)(smem + 32768);       // [2][64*128] = 32 KB
    float* k2tA = (float*)(smem + 65536);  // [2][128] = 1 KB
    float* mbuf = (float*)smem;            // epilogue merge: 256 x 40 f32 = 40 KB

    const int tid = threadIdx.x;
    const int grp = tid >> 8;
    const int t2 = tid & 255;
    const int lane = tid & 63;
    const int w4 = t2 >> 6;
    const int l15 = lane & 15, l4 = lane >> 4;
    f16* Ks = KsA + grp * (128 * 64);
    f16* Vs = VsA + grp * (64 * 128);
    float* k2t = k2tA + grp * 128;

    const int fid = blockIdx.y * 8 + blockIdx.x;
    const int qt = (fid >> 3) & 7;
    const int bh = (fid & 7) * 8 + (fid >> 6);
    const int b = bh >> 4, h = bh & 15;
    const int wq = w4 * 32;
    const int hcol = h * 64;
    const int qrow0 = b * 1024 + qt * 128;
    const f16* vTh = vT + (size_t)hcol * 4096 + b * 1024;  // vT[d=1024][tok=4096]

    const int sr = t2 >> 3, sc0 = (t2 & 7) * 8;
    const int vr = t2 >> 4, vc0 = (t2 & 15) * 8;
    const int vsw = (vr & 7) << 3;
    const int fsw = (l15 & 7) << 3;

    f16x8 bq[2][2];
#pragma unroll
    for (int m = 0; m < 2; ++m)
#pragma unroll
        for (int ks = 0; ks < 2; ++ks)
            bq[m][ks] = *(const f16x8*)&qs[(size_t)(qrow0 + wq + m * 16 + l15) * 1024 + hcol + ks * 32 + l4 * 8];
    float q2m[2];
#pragma unroll
    for (int m = 0; m < 2; ++m) q2m[m] = q2c2[(size_t)bh * 1024 + qt * 128 + wq + m * 16 + l15];

    f32x4 accv[2][4] = {};
    f32x4 dacc[2] = {};
    const f16 one = (f16)1.f;
    const f16x8 ones8 = {one, one, one, one, one, one, one, one};

    f16x8 kreg[4], vreg[4];
    float k2reg = 0.f;
#define ISSUE_LOADS(KT)                                                                                      \
    {                                                                                                        \
        _Pragma("unroll") for (int i = 0; i < 4; ++i)                                                        \
            kreg[i] = *(const f16x8*)&kb[(size_t)(b * 1024 + (KT) * 128 + sr + i * 32) * 1024 + hcol + sc0]; \
        _Pragma("unroll") for (int j = 0; j < 4; ++j)                                                        \
            vreg[j] = *(const f16x8*)&vTh[(size_t)(vr + j * 16) * 4096 + (KT) * 128 + vc0];                  \
        k2reg = (t2 < 128) ? k2c2[(size_t)bh * 1024 + (KT) * 128 + t2] : 0.f;                                \
    }

    ISSUE_LOADS(grp * 4)

    for (int ktl = 0; ktl < 4; ++ktl) {
        __syncthreads();
#pragma unroll
        for (int i = 0; i < 4; ++i) {
            const int kap = sr + i * 32;
            const int s = ((kap >> 5) & 3) * 32 + ((kap >> 2) & 1) * 16 + ((kap >> 3) & 3) * 4 + (kap & 3);
            *(f16x8*)&Ks[s * 64 + (sc0 ^ ((s & 7) << 3))] = kreg[i];
        }
#pragma unroll
        for (int j = 0; j < 4; ++j) *(f16x8*)&Vs[(vr + j * 16) * 128 + (vc0 ^ vsw)] = vreg[j];
        if (t2 < 128) k2t[t2] = k2reg;
        __syncthreads();
        if (ktl < 3) ISSUE_LOADS(grp * 4 + ktl + 1)

#pragma unroll
        for (int kk = 0; kk < 4; ++kk) {
            unsigned um[2][4];
#pragma unroll
            for (int half = 0; half < 2; ++half) {
                const int n = kk * 2 + half;
                f16x8 kf0 = *(const f16x8*)&Ks[(n * 16 + l15) * 64 + ((l4 * 8) ^ fsw)];
                f16x8 kf1 = *(const f16x8*)&Ks[(n * 16 + l15) * 64 + ((32 + l4 * 8) ^ fsw)];
                f32x4 k2q = *(const f32x4*)&k2t[kk * 32 + l4 * 8 + half * 4];
#pragma unroll
                for (int m = 0; m < 2; ++m) {
                    f32x4 c0;
#pragma unroll
                    for (int r = 0; r < 4; ++r) c0[r] = q2m[m] + k2q[r];
                    f32x4 st = MFMA16(kf0, bq[m][0], c0);
                    st = MFMA16(kf1, bq[m][1], st);
                    float p0 = EXP2F(SQRTF(fmaxf(st[0], 0.f)));
                    float p1 = EXP2F(SQRTF(fmaxf(st[1], 0.f)));
                    float p2 = EXP2F(SQRTF(fmaxf(st[2], 0.f)));
                    float p3 = EXP2F(SQRTF(fmaxf(st[3], 0.f)));
                    f16x2 lo = {(f16)p0, (f16)p1};
                    f16x2 hi = {(f16)p2, (f16)p3};
                    um[m][half * 2] = __builtin_bit_cast(unsigned, lo);
                    um[m][half * 2 + 1] = __builtin_bit_cast(unsigned, hi);
                }
            }
            f16x8 ap[2];
#pragma unroll
            for (int m = 0; m < 2; ++m) {
                uint4 u = {um[m][0], um[m][1], um[m][2], um[m][3]};
                ap[m] = __builtin_bit_cast(f16x8, u);
            }
            __builtin_amdgcn_s_setprio(1);
#pragma unroll
            for (int m = 0; m < 2; ++m) dacc[m] = MFMA16(ap[m], ones8, dacc[m]);
#pragma unroll
            for (int n2 = 0; n2 < 4; ++n2) {
                f16x8 bv = *(const f16x8*)&Vs[(n2 * 16 + l15) * 128 + ((kk * 32 + l4 * 8) ^ fsw)];
#pragma unroll
                for (int m = 0; m < 2; ++m) accv[m][n2] = MFMA16(ap[m], bv, accv[m][n2]);
            }
            __builtin_amdgcn_s_setprio(0);
        }
    }

    // merge the two K-halves: grp 1 publishes, grp 0 reduces + stores
    __syncthreads();
    if (grp) {
        float* p = mbuf + t2 * 40;
#pragma unroll
        for (int m = 0; m < 2; ++m)
#pragma unroll
            for (int n2 = 0; n2 < 4; ++n2) *(f32x4*)(p + (m * 4 + n2) * 4) = accv[m][n2];
        *(f32x4*)(p + 32) = dacc[0];
        *(f32x4*)(p + 36) = dacc[1];
    }
    __syncthreads();
    if (!grp) {
        float* p = mbuf + t2 * 40;
#pragma unroll
        for (int m = 0; m < 2; ++m)
#pragma unroll
            for (int n2 = 0; n2 < 4; ++n2) accv[m][n2] += *(const f32x4*)(p + (m * 4 + n2) * 4);
        dacc[0] += *(const f32x4*)(p + 32);
        dacc[1] += *(const f32x4*)(p + 36);
#pragma unroll
        for (int m = 0; m < 2; ++m)
#pragma unroll
            for (int r = 0; r < 4; ++r) {
                const float rd = 1.0f / dacc[m][r];
#pragma unroll
                for (int n2 = 0; n2 < 4; ++n2)
                    out[(size_t)(qrow0 + wq + m * 16 + l4 * 4 + r) * 1024 + hcol + n2 * 16 + l15] =
                        (f16)(accv[m][n2][r] * rd);
            }
    }
}

extern "C" void kernel_launch(void* const* d_in, const int* in_sizes, int n_in,
                              void* d_out, int out_size, void* d_ws, size_t ws_size,
                              hipStream_t stream) {
    const float* Xq = (const float*)d_in[0];
    const float* Xk = (const float*)d_in[1];
    const float* Xv = (const float*)d_in[2];
    const float* Wq = (const float*)d_in[3];
    const float* Wk = (const float*)d_in[4];
    const float* Wv = (const float*)d_in[5];
    const float* Wp = (const float*)d_in[6];
    const float* bp = (const float*)d_in[7];
    float* out = (float*)d_out;

    char* ws = (char*)d_ws;
    f16* W16 = (f16*)(ws);                      // 4M f16
    f16* X16 = (f16*)(ws + (8ull << 20));       // Xq16|Xk16|Xv16
    f16* qb = (f16*)(ws + (32ull << 20));       // qk out base (z-stride 4M f16)
    f16* kb = (f16*)(ws + (40ull << 20));
    f16* vTb = (f16*)(ws + (48ull << 20));
    f16* attnout = (f16*)(ws + (56ull << 20));
    (void)kb;
    // norms scratch in d_out head; written each launch before use, overwritten by final GEMM
    float* q2c2 = out;
    float* k2c2 = out + 65536;

    const float qsc = (float)(-2.0 * C2d);
    const float ns_q = (float)(1.0 / (4.0 * C2d));
    const float ns_k = (float)C2d;

    cvt_all<<<8192, 256, 0, stream>>>(Xq, Xk, Xv, Wq, Wk, Wv, Wp, W16, X16);

    // fused q-proj + k-proj + vT (768 blocks)
    gemm_qkv<<<768, 256, 0, stream>>>(X16, W16, qb, vTb, q2c2, qsc, ns_q, ns_k);

    attn<<<dim3(8, 64), 512, 0, stream>>>(qb, kb, vTb, q2c2, k2c2, attnout);

    gemm_fin<<<512, 256, 0, stream>>>(attnout, W16 + 3 * (1u << 20), out, bp);
}

// Round 12
// 105.713 us; speedup vs baseline: 1.1286x; 1.0714x over previous
//
#include <hip/hip_runtime.h>

// MultiHeadAttentionForViTDiscriminator: B=4, C=1024, D=1024, H=16, DH=64
// R12: one-line fix of R11 -- attn launch_bounds (512,4) -> (512,2).
//      (512,4) forced a 64-VGPR cap -> 51MB/dispatch spill traffic (same
//      failure as R6's (256,4); hipcc's min-waves arg is harsher than the
//      per-SIMD arithmetic suggests -- never set it above 2 again).
//      Everything else byte-identical to R11.
// Workspace (64 MB):
//   [0,8M) W16  [8,32M) X16 (Xq|Xk|Xv f16)  [32,40M) qb  [40,48M) kb
//   [48,56M) vTb  [56,64M) attnout
//   norms q2c2/k2c2 (2 x 256KB f32) live in d_out's head (dead before final GEMM).

typedef _Float16 f16;
typedef __attribute__((ext_vector_type(2))) _Float16 f16x2;
typedef __attribute__((ext_vector_type(8))) _Float16 f16x8;
typedef __attribute__((ext_vector_type(4))) float f32x4;
typedef __attribute__((ext_vector_type(16))) float f32x16;

#define MFMA16(a, b, c) __builtin_amdgcn_mfma_f32_16x16x32_f16((a), (b), (c), 0, 0, 0)
#define MFMA32(a, b, c) __builtin_amdgcn_mfma_f32_32x32x16_f16((a), (b), (c), 0, 0, 0)

constexpr double LOG2E = 1.4426950408889634;
constexpr double C2d = 0.015625 * LOG2E * LOG2E;  // (DH^-0.5 * log2e)^2

#if __has_builtin(__builtin_amdgcn_exp2f)
#define EXP2F(x) __builtin_amdgcn_exp2f(x)
#else
#define EXP2F(x) exp2f(x)
#endif
#if __has_builtin(__builtin_amdgcn_sqrtf)
#define SQRTF(x) __builtin_amdgcn_sqrtf(x)
#else
#define SQRTF(x) sqrtf(x)
#endif

__device__ __forceinline__ void stage16(const void* g, void* lds_base_uniform) {
#if __has_builtin(__builtin_amdgcn_global_load_lds)
    __builtin_amdgcn_global_load_lds((const __attribute__((address_space(1))) void*)g,
                                     (__attribute__((address_space(3))) void*)lds_base_uniform,
                                     16, 0, 0);
#else
    const int lane = threadIdx.x & 63;
    *(f16x8*)((f16*)lds_base_uniform + lane * 8) = *(const f16x8*)g;
#endif
}

__device__ __forceinline__ f16x8 cvt8v(f32x4 a, f32x4 b) {
    f16x8 o;
    o[0] = (f16)a[0]; o[1] = (f16)a[1]; o[2] = (f16)a[2]; o[3] = (f16)a[3];
    o[4] = (f16)b[0]; o[5] = (f16)b[1]; o[6] = (f16)b[2]; o[7] = (f16)b[3];
    return o;
}

// One conversion kernel for all fp32->f16 inputs. 8192 blocks x 2048 elems = 16M.
__global__ __launch_bounds__(256) void cvt_all(const float* __restrict__ Xq,
                                               const float* __restrict__ Xk,
                                               const float* __restrict__ Xv,
                                               const float* __restrict__ Wq,
                                               const float* __restrict__ Wk,
                                               const float* __restrict__ Wv,
                                               const float* __restrict__ Wp,
                                               f16* __restrict__ W16,
                                               f16* __restrict__ X16) {
    const size_t idx = (size_t)blockIdx.x * 2048 + threadIdx.x * 8;
    const size_t M4 = 4ull << 20, M1 = 1ull << 20;
    const float* s;
    f16* d;
    if (idx < 3 * M4) {
        if (idx < M4) s = Xq + idx;
        else if (idx < 2 * M4) s = Xk + (idx - M4);
        else s = Xv + (idx - 2 * M4);
        d = X16 + idx;
    } else {
        size_t wi = idx - 3 * M4;
        if (wi < M1) s = Wq + wi;
        else if (wi < 2 * M1) s = Wk + (wi - M1);
        else if (wi < 3 * M1) s = Wv + (wi - 2 * M1);
        else s = Wp + (wi - 3 * M1);
        d = W16 + wi;
    }
    f32x4 a = *(const f32x4*)s;
    f32x4 b = *(const f32x4*)(s + 4);
    *(f16x8*)d = cvt8v(a, b);
}

// 128x128 GEMM body (R10-verified): BK=64, 4 waves (2x2), 64x64 wave tile,
// MFMA32, XOR-swizzled LDS via pre-swizzled gload_lds source.
template <bool NORMS, bool F32OUT>
__device__ __forceinline__ void gemm128(f16* As, f16* Bs,
                                        const f16* __restrict__ Ap,
                                        const f16* __restrict__ Bp,
                                        f16* __restrict__ Cop,
                                        float* __restrict__ Cf,
                                        const float* __restrict__ bias,
                                        float* __restrict__ nrmp,
                                        float osc, float nscale,
                                        int row0, int col0, int N, int K) {
    const int tid = threadIdx.x;
    const int lane = tid & 63;
    const int w = tid >> 6;
    const int l31 = lane & 31, l5 = lane >> 5;
    const int wr = (w >> 1) * 64, wc = (w & 1) * 64;

    f32x16 acc[2][2] = {};

    for (int kt = 0; kt < K; kt += 64) {
        __syncthreads();
#pragma unroll
        for (int t = 0; t < 4; ++t) {
            const int rb = w * 32 + t * 8;
            const int rr = rb + (lane >> 3);
            const int gs = (lane & 7) ^ (rr & 7);
            stage16(&Ap[(size_t)(row0 + rr) * K + kt + gs * 8], &As[rb * 64]);
            stage16(&Bp[(size_t)(col0 + rr) * K + kt + gs * 8], &Bs[rb * 64]);
        }
        __syncthreads();
#pragma unroll
        for (int ks = 0; ks < 4; ++ks) {
            const int gq = ks * 2 + l5;
            f16x8 af[2], bf[2];
#pragma unroll
            for (int mr = 0; mr < 2; ++mr)
                af[mr] = *(const f16x8*)&As[(wr + mr * 32 + l31) * 64 + ((gq ^ (l31 & 7)) * 8)];
#pragma unroll
            for (int n2 = 0; n2 < 2; ++n2)
                bf[n2] = *(const f16x8*)&Bs[(wc + n2 * 32 + l31) * 64 + ((gq ^ (l31 & 7)) * 8)];
#pragma unroll
            for (int mr = 0; mr < 2; ++mr)
#pragma unroll
                for (int n2 = 0; n2 < 2; ++n2) acc[mr][n2] = MFMA32(af[mr], bf[n2], acc[mr][n2]);
        }
    }

    const int cc0 = col0 + wc + l31;
    const int cc1 = col0 + wc + 32 + l31;
    const int hh = (col0 + wc) >> 6;
#pragma unroll
    for (int mr = 0; mr < 2; ++mr)
#pragma unroll
        for (int j = 0; j < 16; ++j) {
            const int rr = row0 + wr + mr * 32 + (j & 3) + 8 * (j >> 2) + 4 * l5;
            if (F32OUT) {
                Cf[(size_t)rr * N + cc0] = acc[mr][0][j] + bias[cc0];
                Cf[(size_t)rr * N + cc1] = acc[mr][1][j] + bias[cc1];
            } else {
                const f16 h0 = (f16)(acc[mr][0][j] * osc);
                const f16 h1 = (f16)(acc[mr][1][j] * osc);
                if (NORMS) {
                    float v0 = (float)h0, v1 = (float)h1;
                    float s = v0 * v0 + v1 * v1;
                    s += __shfl_xor(s, 1);
                    s += __shfl_xor(s, 2);
                    s += __shfl_xor(s, 4);
                    s += __shfl_xor(s, 8);
                    s += __shfl_xor(s, 16);
                    if (l31 == 0)
                        nrmp[(size_t)((rr >> 10) * 16 + hh) * 1024 + (rr & 1023)] = s * nscale;
                }
                Cop[(size_t)rr * N + cc0] = h0;
                Cop[(size_t)rr * N + cc1] = h1;
            }
        }
}

// Fused qk + vT launch: bid<512 -> qk (z=bid>>8); bid>=512 -> vT.
__global__ __launch_bounds__(256, 2) void gemm_qkv(const f16* __restrict__ X16,
                                                   const f16* __restrict__ W16,
                                                   f16* __restrict__ qb_base,
                                                   f16* __restrict__ vTb,
                                                   float* __restrict__ nrm,
                                                   float qsc, float ns_q, float ns_k) {
    __shared__ __attribute__((aligned(16))) f16 As[128 * 64];
    __shared__ __attribute__((aligned(16))) f16 Bs[128 * 64];
    const int bid = blockIdx.x;
    if (bid < 512) {
        const int z = bid >> 8;
        const int f = bid & 255;
        const int g = (f & 7) * 32 + (f >> 3);
        const int row0 = (g >> 3) * 128, col0 = (g & 7) * 128;
        gemm128<true, false>(As, Bs,
                             X16 + (size_t)z * (4u << 20), W16 + (size_t)z * (1u << 20),
                             qb_base + (size_t)z * (4u << 20), nullptr, nullptr,
                             nrm + (size_t)z * 65536,
                             z ? 1.0f : qsc, z ? ns_k : ns_q, row0, col0, 1024, 1024);
    } else {
        const int f = bid - 512;
        const int g = (f & 7) * 32 + (f >> 3);
        const int row0 = (g >> 5) * 128, col0 = (g & 31) * 128;
        gemm128<false, false>(As, Bs,
                              W16 + 2 * (1u << 20), X16 + 2 * (4u << 20),
                              vTb, nullptr, nullptr, nullptr,
                              1.0f, 0.f, row0, col0, 4096, 1024);
    }
}

// Final projection: 64x128 tiles, 512 blocks (2/CU). f32 out + bias.
__global__ __launch_bounds__(256, 2) void gemm_fin(const f16* __restrict__ A,
                                                   const f16* __restrict__ B,
                                                   float* __restrict__ Cf,
                                                   const float* __restrict__ bias) {
    __shared__ __attribute__((aligned(16))) f16 As[64 * 64];
    __shared__ __attribute__((aligned(16))) f16 Bs[128 * 64];
    const int tid = threadIdx.x;
    const int lane = tid & 63;
    const int w = tid >> 6;
    const int l31 = lane & 31, l5 = lane >> 5;
    const int wr = (w & 1) * 32, wc = (w >> 1) * 64;
    const int f = blockIdx.x;
    const int g = (f & 7) * 64 + (f >> 3);
    const int row0 = (g >> 3) * 64, col0 = (g & 7) * 128;
    const int K = 1024, N = 1024;

    f32x16 acc[2] = {};

    for (int kt = 0; kt < K; kt += 64) {
        __syncthreads();
#pragma unroll
        for (int t = 0; t < 2; ++t) {  // A: 64 rows
            const int rb = w * 16 + t * 8;
            const int rr = rb + (lane >> 3);
            const int gs = (lane & 7) ^ (rr & 7);
            stage16(&A[(size_t)(row0 + rr) * K + kt + gs * 8], &As[rb * 64]);
        }
#pragma unroll
        for (int t = 0; t < 4; ++t) {  // B: 128 rows
            const int rb = w * 32 + t * 8;
            const int rr = rb + (lane >> 3);
            const int gs = (lane & 7) ^ (rr & 7);
            stage16(&B[(size_t)(col0 + rr) * K + kt + gs * 8], &Bs[rb * 64]);
        }
        __syncthreads();
#pragma unroll
        for (int ks = 0; ks < 4; ++ks) {
            const int gq = ks * 2 + l5;
            f16x8 af = *(const f16x8*)&As[(wr + l31) * 64 + ((gq ^ (l31 & 7)) * 8)];
#pragma unroll
            for (int n2 = 0; n2 < 2; ++n2) {
                f16x8 bf = *(const f16x8*)&Bs[(wc + n2 * 32 + l31) * 64 + ((gq ^ (l31 & 7)) * 8)];
                acc[n2] = MFMA32(af, bf, acc[n2]);
            }
        }
    }

    const int cc0 = col0 + wc + l31;
    const int cc1 = col0 + wc + 32 + l31;
#pragma unroll
    for (int j = 0; j < 16; ++j) {
        const int rr = row0 + wr + (j & 3) + 8 * (j >> 2) + 4 * l5;
        Cf[(size_t)rr * N + cc0] = acc[0][j] + bias[cc0];
        Cf[(size_t)rr * N + cc1] = acc[1][j] + bias[cc1];
    }
}

// Distance attention: 512 threads, 2 K-groups (grp 0: keys 0-511, grp 1: 512-1023),
// per-group Ks/Vs/k2, shared barriers (same trip count), LDS partial merge.
// launch_bounds (512,2): VGPR cap 256 >= ~110 need (R11's (512,4) forced 64 -> spill).
__global__ __launch_bounds__(512, 2) void attn(const f16* __restrict__ qs,
                                               const f16* __restrict__ kb,
                                               const f16* __restrict__ vT,
                                               const float* __restrict__ q2c2,
                                               const float* __restrict__ k2c2,
                                               f16* __restrict__ out) {
    __shared__ __attribute__((aligned(16))) char smem[67 * 1024];
    f16* KsA = (f16*)smem;                 // [2][128*64] = 32 KB
    f16* VsA = (f16*)(smem + 32768);       // [2][64*128] = 32 KB
    float* k2tA = (float*)(smem + 65536);  // [2][128] = 1 KB
    float* mbuf = (float*)smem;            // epilogue merge: 256 x 40 f32 = 40 KB

    const int tid = threadIdx.x;
    const int grp = tid >> 8;
    const int t2 = tid & 255;
    const int lane = tid & 63;
    const int w4 = t2 >> 6;
    const int l15 = lane & 15, l4 = lane >> 4;
    f16* Ks = KsA + grp * (128 * 64);
    f16* Vs = VsA + grp * (64 * 128);
    float* k2t = k2tA + grp * 128;

    const int fid = blockIdx.y * 8 + blockIdx.x;
    const int qt = (fid >> 3) & 7;
    const int bh = (fid & 7) * 8 + (fid >> 6);
    const int b = bh >> 4, h = bh & 15;
    const int wq = w4 * 32;
    const int hcol = h * 64;
    const int qrow0 = b * 1024 + qt * 128;
    const f16* vTh = vT + (size_t)hcol * 4096 + b * 1024;  // vT[d=1024][tok=4096]

    const int sr = t2 >> 3, sc0 = (t2 & 7) * 8;
    const int vr = t2 >> 4, vc0 = (t2 & 15) * 8;
    const int vsw = (vr & 7) << 3;
    const int fsw = (l15 & 7) << 3;

    f16x8 bq[2][2];
#pragma unroll
    for (int m = 0; m < 2; ++m)
#pragma unroll
        for (int ks = 0; ks < 2; ++ks)
            bq[m][ks] = *(const f16x8*)&qs[(size_t)(qrow0 + wq + m * 16 + l15) * 1024 + hcol + ks * 32 + l4 * 8];
    float q2m[2];
#pragma unroll
    for (int m = 0; m < 2; ++m) q2m[m] = q2c2[(size_t)bh * 1024 + qt * 128 + wq + m * 16 + l15];

    f32x4 accv[2][4] = {};
    f32x4 dacc[2] = {};
    const f16 one = (f16)1.f;
    const f16x8 ones8 = {one, one, one, one, one, one, one, one};

    f16x8 kreg[4], vreg[4];
    float k2reg = 0.f;
#define ISSUE_LOADS(KT)                                                                                      \
    {                                                                                                        \
        _Pragma("unroll") for (int i = 0; i < 4; ++i)                                                        \
            kreg[i] = *(const f16x8*)&kb[(size_t)(b * 1024 + (KT) * 128 + sr + i * 32) * 1024 + hcol + sc0]; \
        _Pragma("unroll") for (int j = 0; j < 4; ++j)                                                        \
            vreg[j] = *(const f16x8*)&vTh[(size_t)(vr + j * 16) * 4096 + (KT) * 128 + vc0];                  \
        k2reg = (t2 < 128) ? k2c2[(size_t)bh * 1024 + (KT) * 128 + t2] : 0.f;                                \
    }

    ISSUE_LOADS(grp * 4)

    for (int ktl = 0; ktl < 4; ++ktl) {
        __syncthreads();
#pragma unroll
        for (int i = 0; i < 4; ++i) {
            const int kap = sr + i * 32;
            const int s = ((kap >> 5) & 3) * 32 + ((kap >> 2) & 1) * 16 + ((kap >> 3) & 3) * 4 + (kap & 3);
            *(f16x8*)&Ks[s * 64 + (sc0 ^ ((s & 7) << 3))] = kreg[i];
        }
#pragma unroll
        for (int j = 0; j < 4; ++j) *(f16x8*)&Vs[(vr + j * 16) * 128 + (vc0 ^ vsw)] = vreg[j];
        if (t2 < 128) k2t[t2] = k2reg;
        __syncthreads();
        if (ktl < 3) ISSUE_LOADS(grp * 4 + ktl + 1)

#pragma unroll
        for (int kk = 0; kk < 4; ++kk) {
            unsigned um[2][4];
#pragma unroll
            for (int half = 0; half < 2; ++half) {
                const int n = kk * 2 + half;
                f16x8 kf0 = *(const f16x8*)&Ks[(n * 16 + l15) * 64 + ((l4 * 8) ^ fsw)];
                f16x8 kf1 = *(const f16x8*)&Ks[(n * 16 + l15) * 64 + ((32 + l4 * 8) ^ fsw)];
                f32x4 k2q = *(const f32x4*)&k2t[kk * 32 + l4 * 8 + half * 4];
#pragma unroll
                for (int m = 0; m < 2; ++m) {
                    f32x4 c0;
#pragma unroll
                    for (int r = 0; r < 4; ++r) c0[r] = q2m[m] + k2q[r];
                    f32x4 st = MFMA16(kf0, bq[m][0], c0);
                    st = MFMA16(kf1, bq[m][1], st);
                    float p0 = EXP2F(SQRTF(fmaxf(st[0], 0.f)));
                    float p1 = EXP2F(SQRTF(fmaxf(st[1], 0.f)));
                    float p2 = EXP2F(SQRTF(fmaxf(st[2], 0.f)));
                    float p3 = EXP2F(SQRTF(fmaxf(st[3], 0.f)));
                    f16x2 lo = {(f16)p0, (f16)p1};
                    f16x2 hi = {(f16)p2, (f16)p3};
                    um[m][half * 2] = __builtin_bit_cast(unsigned, lo);
                    um[m][half * 2 + 1] = __builtin_bit_cast(unsigned, hi);
                }
            }
            f16x8 ap[2];
#pragma unroll
            for (int m = 0; m < 2; ++m) {
                uint4 u = {um[m][0], um[m][1], um[m][2], um[m][3]};
                ap[m] = __builtin_bit_cast(f16x8, u);
            }
            __builtin_amdgcn_s_setprio(1);
#pragma unroll
            for (int m = 0; m < 2; ++m) dacc[m] = MFMA16(ap[m], ones8, dacc[m]);
#pragma unroll
            for (int n2 = 0; n2 < 4; ++n2) {
                f16x8 bv = *(const f16x8*)&Vs[(n2 * 16 + l15) * 128 + ((kk * 32 + l4 * 8) ^ fsw)];
#pragma unroll
                for (int m = 0; m < 2; ++m) accv[m][n2] = MFMA16(ap[m], bv, accv[m][n2]);
            }
            __builtin_amdgcn_s_setprio(0);
        }
    }

    // merge the two K-halves: grp 1 publishes, grp 0 reduces + stores
    __syncthreads();
    if (grp) {
        float* p = mbuf + t2 * 40;
#pragma unroll
        for (int m = 0; m < 2; ++m)
#pragma unroll
            for (int n2 = 0; n2 < 4; ++n2) *(f32x4*)(p + (m * 4 + n2) * 4) = accv[m][n2];
        *(f32x4*)(p + 32) = dacc[0];
        *(f32x4*)(p + 36) = dacc[1];
    }
    __syncthreads();
    if (!grp) {
        float* p = mbuf + t2 * 40;
#pragma unroll
        for (int m = 0; m < 2; ++m)
#pragma unroll
            for (int n2 = 0; n2 < 4; ++n2) accv[m][n2] += *(const f32x4*)(p + (m * 4 + n2) * 4);
        dacc[0] += *(const f32x4*)(p + 32);
        dacc[1] += *(const f32x4*)(p + 36);
#pragma unroll
        for (int m = 0; m < 2; ++m)
#pragma unroll
            for (int r = 0; r < 4; ++r) {
                const float rd = 1.0f / dacc[m][r];
#pragma unroll
                for (int n2 = 0; n2 < 4; ++n2)
                    out[(size_t)(qrow0 + wq + m * 16 + l4 * 4 + r) * 1024 + hcol + n2 * 16 + l15] =
                        (f16)(accv[m][n2][r] * rd);
            }
    }
}

extern "C" void kernel_launch(void* const* d_in, const int* in_sizes, int n_in,
                              void* d_out, int out_size, void* d_ws, size_t ws_size,
                              hipStream_t stream) {
    const float* Xq = (const float*)d_in[0];
    const float* Xk = (const float*)d_in[1];
    const float* Xv = (const float*)d_in[2];
    const float* Wq = (const float*)d_in[3];
    const float* Wk = (const float*)d_in[4];
    const float* Wv = (const float*)d_in[5];
    const float* Wp = (const float*)d_in[6];
    const float* bp = (const float*)d_in[7];
    float* out = (float*)d_out;

    char* ws = (char*)d_ws;
    f16* W16 = (f16*)(ws);                      // 4M f16
    f16* X16 = (f16*)(ws + (8ull << 20));       // Xq16|Xk16|Xv16
    f16* qb = (f16*)(ws + (32ull << 20));       // qk out base (z-stride 4M f16)
    f16* kb = (f16*)(ws + (40ull << 20));
    f16* vTb = (f16*)(ws + (48ull << 20));
    f16* attnout = (f16*)(ws + (56ull << 20));
    (void)kb;
    // norms scratch in d_out head; written each launch before use, overwritten by final GEMM
    float* q2c2 = out;
    float* k2c2 = out + 65536;

    const float qsc = (float)(-2.0 * C2d);
    const float ns_q = (float)(1.0 / (4.0 * C2d));
    const float ns_k = (float)C2d;

    cvt_all<<<8192, 256, 0, stream>>>(Xq, Xk, Xv, Wq, Wk, Wv, Wp, W16, X16);

    // fused q-proj + k-proj + vT (768 blocks)
    gemm_qkv<<<768, 256, 0, stream>>>(X16, W16, qb, vTb, q2c2, qsc, ns_q, ns_k);

    attn<<<dim3(8, 64), 512, 0, stream>>>(qb, kb, vTb, q2c2, k2c2, attnout);

    gemm_fin<<<512, 256, 0, stream>>>(attnout, W16 + 3 * (1u << 20), out, bp);
}

// Round 13
// 103.853 us; speedup vs baseline: 1.1488x; 1.0179x over previous
//
#include <hip/hip_runtime.h>

// MultiHeadAttentionForViTDiscriminator: B=4, C=1024, D=1024, H=16, DH=64
// R13: attn occupancy restructure -- 1024 blocks x 256 threads, 64 q-rows/block,
//      single K-group (8 K-tiles), LDS 68.6->33.3KB => 4 blocks/CU (16 waves),
//      4-wave barrier scope, no merge epilogue, setprio removed (lockstep
//      => null/negative per m190). Inner math = m=1 specialization of the
//      R12-verified code. gemm_qkv / gemm_fin / cvt_all unchanged.
// Workspace (64 MB):
//   [0,8M) W16  [8,32M) X16 (Xq|Xk|Xv f16)  [32,40M) qb  [40,48M) kb
//   [48,56M) vTb  [56,64M) attnout
//   norms q2c2/k2c2 (2 x 256KB f32) live in d_out's head (dead before final GEMM).

typedef _Float16 f16;
typedef __attribute__((ext_vector_type(2))) _Float16 f16x2;
typedef __attribute__((ext_vector_type(8))) _Float16 f16x8;
typedef __attribute__((ext_vector_type(4))) float f32x4;
typedef __attribute__((ext_vector_type(16))) float f32x16;

#define MFMA16(a, b, c) __builtin_amdgcn_mfma_f32_16x16x32_f16((a), (b), (c), 0, 0, 0)
#define MFMA32(a, b, c) __builtin_amdgcn_mfma_f32_32x32x16_f16((a), (b), (c), 0, 0, 0)

constexpr double LOG2E = 1.4426950408889634;
constexpr double C2d = 0.015625 * LOG2E * LOG2E;  // (DH^-0.5 * log2e)^2

#if __has_builtin(__builtin_amdgcn_exp2f)
#define EXP2F(x) __builtin_amdgcn_exp2f(x)
#else
#define EXP2F(x) exp2f(x)
#endif
#if __has_builtin(__builtin_amdgcn_sqrtf)
#define SQRTF(x) __builtin_amdgcn_sqrtf(x)
#else
#define SQRTF(x) sqrtf(x)
#endif

__device__ __forceinline__ void stage16(const void* g, void* lds_base_uniform) {
#if __has_builtin(__builtin_amdgcn_global_load_lds)
    __builtin_amdgcn_global_load_lds((const __attribute__((address_space(1))) void*)g,
                                     (__attribute__((address_space(3))) void*)lds_base_uniform,
                                     16, 0, 0);
#else
    const int lane = threadIdx.x & 63;
    *(f16x8*)((f16*)lds_base_uniform + lane * 8) = *(const f16x8*)g;
#endif
}

__device__ __forceinline__ f16x8 cvt8v(f32x4 a, f32x4 b) {
    f16x8 o;
    o[0] = (f16)a[0]; o[1] = (f16)a[1]; o[2] = (f16)a[2]; o[3] = (f16)a[3];
    o[4] = (f16)b[0]; o[5] = (f16)b[1]; o[6] = (f16)b[2]; o[7] = (f16)b[3];
    return o;
}

// One conversion kernel for all fp32->f16 inputs. 8192 blocks x 2048 elems = 16M.
__global__ __launch_bounds__(256) void cvt_all(const float* __restrict__ Xq,
                                               const float* __restrict__ Xk,
                                               const float* __restrict__ Xv,
                                               const float* __restrict__ Wq,
                                               const float* __restrict__ Wk,
                                               const float* __restrict__ Wv,
                                               const float* __restrict__ Wp,
                                               f16* __restrict__ W16,
                                               f16* __restrict__ X16) {
    const size_t idx = (size_t)blockIdx.x * 2048 + threadIdx.x * 8;
    const size_t M4 = 4ull << 20, M1 = 1ull << 20;
    const float* s;
    f16* d;
    if (idx < 3 * M4) {
        if (idx < M4) s = Xq + idx;
        else if (idx < 2 * M4) s = Xk + (idx - M4);
        else s = Xv + (idx - 2 * M4);
        d = X16 + idx;
    } else {
        size_t wi = idx - 3 * M4;
        if (wi < M1) s = Wq + wi;
        else if (wi < 2 * M1) s = Wk + (wi - M1);
        else if (wi < 3 * M1) s = Wv + (wi - 2 * M1);
        else s = Wp + (wi - 3 * M1);
        d = W16 + wi;
    }
    f32x4 a = *(const f32x4*)s;
    f32x4 b = *(const f32x4*)(s + 4);
    *(f16x8*)d = cvt8v(a, b);
}

// 128x128 GEMM body (R10-verified): BK=64, 4 waves (2x2), 64x64 wave tile,
// MFMA32, XOR-swizzled LDS via pre-swizzled gload_lds source.
template <bool NORMS, bool F32OUT>
__device__ __forceinline__ void gemm128(f16* As, f16* Bs,
                                        const f16* __restrict__ Ap,
                                        const f16* __restrict__ Bp,
                                        f16* __restrict__ Cop,
                                        float* __restrict__ Cf,
                                        const float* __restrict__ bias,
                                        float* __restrict__ nrmp,
                                        float osc, float nscale,
                                        int row0, int col0, int N, int K) {
    const int tid = threadIdx.x;
    const int lane = tid & 63;
    const int w = tid >> 6;
    const int l31 = lane & 31, l5 = lane >> 5;
    const int wr = (w >> 1) * 64, wc = (w & 1) * 64;

    f32x16 acc[2][2] = {};

    for (int kt = 0; kt < K; kt += 64) {
        __syncthreads();
#pragma unroll
        for (int t = 0; t < 4; ++t) {
            const int rb = w * 32 + t * 8;
            const int rr = rb + (lane >> 3);
            const int gs = (lane & 7) ^ (rr & 7);
            stage16(&Ap[(size_t)(row0 + rr) * K + kt + gs * 8], &As[rb * 64]);
            stage16(&Bp[(size_t)(col0 + rr) * K + kt + gs * 8], &Bs[rb * 64]);
        }
        __syncthreads();
#pragma unroll
        for (int ks = 0; ks < 4; ++ks) {
            const int gq = ks * 2 + l5;
            f16x8 af[2], bf[2];
#pragma unroll
            for (int mr = 0; mr < 2; ++mr)
                af[mr] = *(const f16x8*)&As[(wr + mr * 32 + l31) * 64 + ((gq ^ (l31 & 7)) * 8)];
#pragma unroll
            for (int n2 = 0; n2 < 2; ++n2)
                bf[n2] = *(const f16x8*)&Bs[(wc + n2 * 32 + l31) * 64 + ((gq ^ (l31 & 7)) * 8)];
#pragma unroll
            for (int mr = 0; mr < 2; ++mr)
#pragma unroll
                for (int n2 = 0; n2 < 2; ++n2) acc[mr][n2] = MFMA32(af[mr], bf[n2], acc[mr][n2]);
        }
    }

    const int cc0 = col0 + wc + l31;
    const int cc1 = col0 + wc + 32 + l31;
    const int hh = (col0 + wc) >> 6;
#pragma unroll
    for (int mr = 0; mr < 2; ++mr)
#pragma unroll
        for (int j = 0; j < 16; ++j) {
            const int rr = row0 + wr + mr * 32 + (j & 3) + 8 * (j >> 2) + 4 * l5;
            if (F32OUT) {
                Cf[(size_t)rr * N + cc0] = acc[mr][0][j] + bias[cc0];
                Cf[(size_t)rr * N + cc1] = acc[mr][1][j] + bias[cc1];
            } else {
                const f16 h0 = (f16)(acc[mr][0][j] * osc);
                const f16 h1 = (f16)(acc[mr][1][j] * osc);
                if (NORMS) {
                    float v0 = (float)h0, v1 = (float)h1;
                    float s = v0 * v0 + v1 * v1;
                    s += __shfl_xor(s, 1);
                    s += __shfl_xor(s, 2);
                    s += __shfl_xor(s, 4);
                    s += __shfl_xor(s, 8);
                    s += __shfl_xor(s, 16);
                    if (l31 == 0)
                        nrmp[(size_t)((rr >> 10) * 16 + hh) * 1024 + (rr & 1023)] = s * nscale;
                }
                Cop[(size_t)rr * N + cc0] = h0;
                Cop[(size_t)rr * N + cc1] = h1;
            }
        }
}

// Fused qk + vT launch: bid<512 -> qk (z=bid>>8); bid>=512 -> vT.
__global__ __launch_bounds__(256, 2) void gemm_qkv(const f16* __restrict__ X16,
                                                   const f16* __restrict__ W16,
                                                   f16* __restrict__ qb_base,
                                                   f16* __restrict__ vTb,
                                                   float* __restrict__ nrm,
                                                   float qsc, float ns_q, float ns_k) {
    __shared__ __attribute__((aligned(16))) f16 As[128 * 64];
    __shared__ __attribute__((aligned(16))) f16 Bs[128 * 64];
    const int bid = blockIdx.x;
    if (bid < 512) {
        const int z = bid >> 8;
        const int f = bid & 255;
        const int g = (f & 7) * 32 + (f >> 3);
        const int row0 = (g >> 3) * 128, col0 = (g & 7) * 128;
        gemm128<true, false>(As, Bs,
                             X16 + (size_t)z * (4u << 20), W16 + (size_t)z * (1u << 20),
                             qb_base + (size_t)z * (4u << 20), nullptr, nullptr,
                             nrm + (size_t)z * 65536,
                             z ? 1.0f : qsc, z ? ns_k : ns_q, row0, col0, 1024, 1024);
    } else {
        const int f = bid - 512;
        const int g = (f & 7) * 32 + (f >> 3);
        const int row0 = (g >> 5) * 128, col0 = (g & 31) * 128;
        gemm128<false, false>(As, Bs,
                              W16 + 2 * (1u << 20), X16 + 2 * (4u << 20),
                              vTb, nullptr, nullptr, nullptr,
                              1.0f, 0.f, row0, col0, 4096, 1024);
    }
}

// Final projection: 64x128 tiles, 512 blocks (2/CU). f32 out + bias.
__global__ __launch_bounds__(256, 2) void gemm_fin(const f16* __restrict__ A,
                                                   const f16* __restrict__ B,
                                                   float* __restrict__ Cf,
                                                   const float* __restrict__ bias) {
    __shared__ __attribute__((aligned(16))) f16 As[64 * 64];
    __shared__ __attribute__((aligned(16))) f16 Bs[128 * 64];
    const int tid = threadIdx.x;
    const int lane = tid & 63;
    const int w = tid >> 6;
    const int l31 = lane & 31, l5 = lane >> 5;
    const int wr = (w & 1) * 32, wc = (w >> 1) * 64;
    const int f = blockIdx.x;
    const int g = (f & 7) * 64 + (f >> 3);
    const int row0 = (g >> 3) * 64, col0 = (g & 7) * 128;
    const int K = 1024, N = 1024;

    f32x16 acc[2] = {};

    for (int kt = 0; kt < K; kt += 64) {
        __syncthreads();
#pragma unroll
        for (int t = 0; t < 2; ++t) {  // A: 64 rows
            const int rb = w * 16 + t * 8;
            const int rr = rb + (lane >> 3);
            const int gs = (lane & 7) ^ (rr & 7);
            stage16(&A[(size_t)(row0 + rr) * K + kt + gs * 8], &As[rb * 64]);
        }
#pragma unroll
        for (int t = 0; t < 4; ++t) {  // B: 128 rows
            const int rb = w * 32 + t * 8;
            const int rr = rb + (lane >> 3);
            const int gs = (lane & 7) ^ (rr & 7);
            stage16(&B[(size_t)(col0 + rr) * K + kt + gs * 8], &Bs[rb * 64]);
        }
        __syncthreads();
#pragma unroll
        for (int ks = 0; ks < 4; ++ks) {
            const int gq = ks * 2 + l5;
            f16x8 af = *(const f16x8*)&As[(wr + l31) * 64 + ((gq ^ (l31 & 7)) * 8)];
#pragma unroll
            for (int n2 = 0; n2 < 2; ++n2) {
                f16x8 bf = *(const f16x8*)&Bs[(wc + n2 * 32 + l31) * 64 + ((gq ^ (l31 & 7)) * 8)];
                acc[n2] = MFMA32(af, bf, acc[n2]);
            }
        }
    }

    const int cc0 = col0 + wc + l31;
    const int cc1 = col0 + wc + 32 + l31;
#pragma unroll
    for (int j = 0; j < 16; ++j) {
        const int rr = row0 + wr + (j & 3) + 8 * (j >> 2) + 4 * l5;
        Cf[(size_t)rr * N + cc0] = acc[0][j] + bias[cc0];
        Cf[(size_t)rr * N + cc1] = acc[1][j] + bias[cc1];
    }
}

// Distance attention: 1024 blocks x 256 threads, 64 q-rows/block (4 waves x 16),
// full-K loop (8 tiles of 128 keys). Swapped QK + permuted K slots => in-reg P;
// den via ones-MFMA. LDS 33.3KB => 4 blocks/CU (16 waves/CU).
__global__ __launch_bounds__(256, 2) void attn(const f16* __restrict__ qs,
                                               const f16* __restrict__ kb,
                                               const f16* __restrict__ vT,
                                               const float* __restrict__ q2c2,
                                               const float* __restrict__ k2c2,
                                               f16* __restrict__ out) {
    __shared__ __attribute__((aligned(16))) f16 Ks[128 * 64];  // permuted slots + XOR swizzle
    __shared__ __attribute__((aligned(16))) f16 Vs[64 * 128];  // XOR-swizzled
    __shared__ float k2tile[128];                              // linear (keyed by true k)
    const int tid = threadIdx.x;
    const int lane = tid & 63;
    const int w = tid >> 6;
    const int l15 = lane & 15, l4 = lane >> 4;
    // XCD remap: 8 bh per XCD (K+V+q slices ~3MB, L2-resident)
    const int fid = blockIdx.y * 16 + blockIdx.x;
    const int qt = (fid >> 3) & 15;
    const int bh = (fid & 7) * 8 + (fid >> 7);
    const int b = bh >> 4, h = bh & 15;
    const int wq = w * 16;
    const int hcol = h * 64;
    const int qrow0 = b * 1024 + qt * 64;
    const f16* vTh = vT + (size_t)hcol * 4096 + b * 1024;  // vT[d=1024][tok=4096]

    const int sr = tid >> 3, sc0 = (tid & 7) * 8;   // K staging (keys sr+i*32)
    const int vr = tid >> 4, vc0 = (tid & 15) * 8;  // V staging (rows vr+j*16)
    const int vsw = (vr & 7) << 3;
    const int fsw = (l15 & 7) << 3;                 // fragment-read swizzle

    // Q frags as B-operand (rows wq+l15), pre-scaled by -2*C2
    f16x8 bq[2];
#pragma unroll
    for (int ks = 0; ks < 2; ++ks)
        bq[ks] = *(const f16x8*)&qs[(size_t)(qrow0 + wq + l15) * 1024 + hcol + ks * 32 + l4 * 8];
    const float q2m = q2c2[(size_t)bh * 1024 + qt * 64 + wq + l15];

    f32x4 accv[4] = {};
    f32x4 dacc = {};
    const f16 one = (f16)1.f;
    const f16x8 ones8 = {one, one, one, one, one, one, one, one};

    f16x8 kreg[4], vreg[4];
    float k2reg = 0.f;
#define ISSUE_LOADS(KT)                                                                                      \
    {                                                                                                        \
        _Pragma("unroll") for (int i = 0; i < 4; ++i)                                                        \
            kreg[i] = *(const f16x8*)&kb[(size_t)(b * 1024 + (KT) * 128 + sr + i * 32) * 1024 + hcol + sc0]; \
        _Pragma("unroll") for (int j = 0; j < 4; ++j)                                                        \
            vreg[j] = *(const f16x8*)&vTh[(size_t)(vr + j * 16) * 4096 + (KT) * 128 + vc0];                  \
        k2reg = (tid < 128) ? k2c2[(size_t)bh * 1024 + (KT) * 128 + tid] : 0.f;                              \
    }

    ISSUE_LOADS(0)

    for (int kt = 0; kt < 8; ++kt) {
        __syncthreads();
        // K staging with slot permutation: key kap -> slot s so that QK D-rows
        // deliver PV A-frag k-order.
#pragma unroll
        for (int i = 0; i < 4; ++i) {
            const int kap = sr + i * 32;
            const int s = ((kap >> 5) & 3) * 32 + ((kap >> 2) & 1) * 16 + ((kap >> 3) & 3) * 4 + (kap & 3);
            *(f16x8*)&Ks[s * 64 + (sc0 ^ ((s & 7) << 3))] = kreg[i];
        }
#pragma unroll
        for (int j = 0; j < 4; ++j) *(f16x8*)&Vs[(vr + j * 16) * 128 + (vc0 ^ vsw)] = vreg[j];
        if (tid < 128) k2tile[tid] = k2reg;
        __syncthreads();
        if (kt < 7) ISSUE_LOADS(kt + 1)  // prefetch hides under compute

#pragma unroll
        for (int kk = 0; kk < 4; ++kk) {
            // QK for windows n=2kk, 2kk+1; assemble PV A-frag dwords in-register
            unsigned um[4];
#pragma unroll
            for (int half = 0; half < 2; ++half) {
                const int n = kk * 2 + half;
                f16x8 kf0 = *(const f16x8*)&Ks[(n * 16 + l15) * 64 + ((l4 * 8) ^ fsw)];
                f16x8 kf1 = *(const f16x8*)&Ks[(n * 16 + l15) * 64 + ((32 + l4 * 8) ^ fsw)];
                // true keys at this lane's D-rows: kk*32 + l4*8 + half*4 + r
                f32x4 k2q = *(const f32x4*)&k2tile[kk * 32 + l4 * 8 + half * 4];
                f32x4 c0;
#pragma unroll
                for (int r = 0; r < 4; ++r) c0[r] = q2m + k2q[r];
                f32x4 st = MFMA16(kf0, bq[0], c0);
                st = MFMA16(kf1, bq[1], st);
                float p0 = EXP2F(SQRTF(fmaxf(st[0], 0.f)));
                float p1 = EXP2F(SQRTF(fmaxf(st[1], 0.f)));
                float p2 = EXP2F(SQRTF(fmaxf(st[2], 0.f)));
                float p3 = EXP2F(SQRTF(fmaxf(st[3], 0.f)));
                f16x2 lo = {(f16)p0, (f16)p1};
                f16x2 hi = {(f16)p2, (f16)p3};
                um[half * 2] = __builtin_bit_cast(unsigned, lo);
                um[half * 2 + 1] = __builtin_bit_cast(unsigned, hi);
            }
            uint4 u = {um[0], um[1], um[2], um[3]};
            f16x8 ap = __builtin_bit_cast(f16x8, u);
            // den += P * 1 (ones-column): D row layout == accv row layout
            dacc = MFMA16(ap, ones8, dacc);
            // PV for this kk (B-operand: V^T rows = d = n2*16+l15)
#pragma unroll
            for (int n2 = 0; n2 < 4; ++n2) {
                f16x8 bv = *(const f16x8*)&Vs[(n2 * 16 + l15) * 128 + ((kk * 32 + l4 * 8) ^ fsw)];
                accv[n2] = MFMA16(ap, bv, accv[n2]);
            }
        }
    }

    // dacc[r] = den for q-row (wq + l4*4 + r) -- same row map as accv
#pragma unroll
    for (int r = 0; r < 4; ++r) {
        const float rd = 1.0f / dacc[r];
#pragma unroll
        for (int n2 = 0; n2 < 4; ++n2)
            out[(size_t)(qrow0 + wq + l4 * 4 + r) * 1024 + hcol + n2 * 16 + l15] =
                (f16)(accv[n2][r] * rd);
    }
}

extern "C" void kernel_launch(void* const* d_in, const int* in_sizes, int n_in,
                              void* d_out, int out_size, void* d_ws, size_t ws_size,
                              hipStream_t stream) {
    const float* Xq = (const float*)d_in[0];
    const float* Xk = (const float*)d_in[1];
    const float* Xv = (const float*)d_in[2];
    const float* Wq = (const float*)d_in[3];
    const float* Wk = (const float*)d_in[4];
    const float* Wv = (const float*)d_in[5];
    const float* Wp = (const float*)d_in[6];
    const float* bp = (const float*)d_in[7];
    float* out = (float*)d_out;

    char* ws = (char*)d_ws;
    f16* W16 = (f16*)(ws);                      // 4M f16
    f16* X16 = (f16*)(ws + (8ull << 20));       // Xq16|Xk16|Xv16
    f16* qb = (f16*)(ws + (32ull << 20));       // qk out base (z-stride 4M f16)
    f16* kb = (f16*)(ws + (40ull << 20));
    f16* vTb = (f16*)(ws + (48ull << 20));
    f16* attnout = (f16*)(ws + (56ull << 20));
    (void)kb;
    // norms scratch in d_out head; written each launch before use, overwritten by final GEMM
    float* q2c2 = out;
    float* k2c2 = out + 65536;

    const float qsc = (float)(-2.0 * C2d);
    const float ns_q = (float)(1.0 / (4.0 * C2d));
    const float ns_k = (float)C2d;

    cvt_all<<<8192, 256, 0, stream>>>(Xq, Xk, Xv, Wq, Wk, Wv, Wp, W16, X16);

    // fused q-proj + k-proj + vT (768 blocks)
    gemm_qkv<<<768, 256, 0, stream>>>(X16, W16, qb, vTb, q2c2, qsc, ns_q, ns_k);

    attn<<<dim3(16, 64), 256, 0, stream>>>(qb, kb, vTb, q2c2, k2c2, attnout);

    gemm_fin<<<512, 256, 0, stream>>>(attnout, W16 + 3 * (1u << 20), out, bp);
}

// Round 14
// 102.835 us; speedup vs baseline: 1.1601x; 1.0099x over previous
//
#include <hip/hip_runtime.h>

// MultiHeadAttentionForViTDiscriminator: B=4, C=1024, D=1024, H=16, DH=64
// R14: (1) gemm_qkv L2 maps: z=bid&1 (XCD z-specialization, qk 6->4MB/XCD);
//      vT chunked 4 token-cols x 8 Wv-rows per XCD (8->3MB/XCD).
//      (2) attn ILP: K-frag ping-pong prefetch (kk+1 issued before kk compute)
//      + V-frag reads hoisted above the trans chain (forces ~110 VGPR; the
//      R13 compiler choice of 60 VGPR serialized the chain).
//      Everything else = R13-verified.
// Workspace (64 MB):
//   [0,8M) W16  [8,32M) X16 (Xq|Xk|Xv f16)  [32,40M) qb  [40,48M) kb
//   [48,56M) vTb  [56,64M) attnout
//   norms q2c2/k2c2 (2 x 256KB f32) live in d_out's head (dead before final GEMM).

typedef _Float16 f16;
typedef __attribute__((ext_vector_type(2))) _Float16 f16x2;
typedef __attribute__((ext_vector_type(8))) _Float16 f16x8;
typedef __attribute__((ext_vector_type(4))) float f32x4;
typedef __attribute__((ext_vector_type(16))) float f32x16;

#define MFMA16(a, b, c) __builtin_amdgcn_mfma_f32_16x16x32_f16((a), (b), (c), 0, 0, 0)
#define MFMA32(a, b, c) __builtin_amdgcn_mfma_f32_32x32x16_f16((a), (b), (c), 0, 0, 0)

constexpr double LOG2E = 1.4426950408889634;
constexpr double C2d = 0.015625 * LOG2E * LOG2E;  // (DH^-0.5 * log2e)^2

#if __has_builtin(__builtin_amdgcn_exp2f)
#define EXP2F(x) __builtin_amdgcn_exp2f(x)
#else
#define EXP2F(x) exp2f(x)
#endif
#if __has_builtin(__builtin_amdgcn_sqrtf)
#define SQRTF(x) __builtin_amdgcn_sqrtf(x)
#else
#define SQRTF(x) sqrtf(x)
#endif

__device__ __forceinline__ void stage16(const void* g, void* lds_base_uniform) {
#if __has_builtin(__builtin_amdgcn_global_load_lds)
    __builtin_amdgcn_global_load_lds((const __attribute__((address_space(1))) void*)g,
                                     (__attribute__((address_space(3))) void*)lds_base_uniform,
                                     16, 0, 0);
#else
    const int lane = threadIdx.x & 63;
    *(f16x8*)((f16*)lds_base_uniform + lane * 8) = *(const f16x8*)g;
#endif
}

__device__ __forceinline__ f16x8 cvt8v(f32x4 a, f32x4 b) {
    f16x8 o;
    o[0] = (f16)a[0]; o[1] = (f16)a[1]; o[2] = (f16)a[2]; o[3] = (f16)a[3];
    o[4] = (f16)b[0]; o[5] = (f16)b[1]; o[6] = (f16)b[2]; o[7] = (f16)b[3];
    return o;
}

// One conversion kernel for all fp32->f16 inputs. 8192 blocks x 2048 elems = 16M.
__global__ __launch_bounds__(256) void cvt_all(const float* __restrict__ Xq,
                                               const float* __restrict__ Xk,
                                               const float* __restrict__ Xv,
                                               const float* __restrict__ Wq,
                                               const float* __restrict__ Wk,
                                               const float* __restrict__ Wv,
                                               const float* __restrict__ Wp,
                                               f16* __restrict__ W16,
                                               f16* __restrict__ X16) {
    const size_t idx = (size_t)blockIdx.x * 2048 + threadIdx.x * 8;
    const size_t M4 = 4ull << 20, M1 = 1ull << 20;
    const float* s;
    f16* d;
    if (idx < 3 * M4) {
        if (idx < M4) s = Xq + idx;
        else if (idx < 2 * M4) s = Xk + (idx - M4);
        else s = Xv + (idx - 2 * M4);
        d = X16 + idx;
    } else {
        size_t wi = idx - 3 * M4;
        if (wi < M1) s = Wq + wi;
        else if (wi < 2 * M1) s = Wk + (wi - M1);
        else if (wi < 3 * M1) s = Wv + (wi - 2 * M1);
        else s = Wp + (wi - 3 * M1);
        d = W16 + wi;
    }
    f32x4 a = *(const f32x4*)s;
    f32x4 b = *(const f32x4*)(s + 4);
    *(f16x8*)d = cvt8v(a, b);
}

// 128x128 GEMM body (R10-verified): BK=64, 4 waves (2x2), 64x64 wave tile,
// MFMA32, XOR-swizzled LDS via pre-swizzled gload_lds source.
template <bool NORMS, bool F32OUT>
__device__ __forceinline__ void gemm128(f16* As, f16* Bs,
                                        const f16* __restrict__ Ap,
                                        const f16* __restrict__ Bp,
                                        f16* __restrict__ Cop,
                                        float* __restrict__ Cf,
                                        const float* __restrict__ bias,
                                        float* __restrict__ nrmp,
                                        float osc, float nscale,
                                        int row0, int col0, int N, int K) {
    const int tid = threadIdx.x;
    const int lane = tid & 63;
    const int w = tid >> 6;
    const int l31 = lane & 31, l5 = lane >> 5;
    const int wr = (w >> 1) * 64, wc = (w & 1) * 64;

    f32x16 acc[2][2] = {};

    for (int kt = 0; kt < K; kt += 64) {
        __syncthreads();
#pragma unroll
        for (int t = 0; t < 4; ++t) {
            const int rb = w * 32 + t * 8;
            const int rr = rb + (lane >> 3);
            const int gs = (lane & 7) ^ (rr & 7);
            stage16(&Ap[(size_t)(row0 + rr) * K + kt + gs * 8], &As[rb * 64]);
            stage16(&Bp[(size_t)(col0 + rr) * K + kt + gs * 8], &Bs[rb * 64]);
        }
        __syncthreads();
#pragma unroll
        for (int ks = 0; ks < 4; ++ks) {
            const int gq = ks * 2 + l5;
            f16x8 af[2], bf[2];
#pragma unroll
            for (int mr = 0; mr < 2; ++mr)
                af[mr] = *(const f16x8*)&As[(wr + mr * 32 + l31) * 64 + ((gq ^ (l31 & 7)) * 8)];
#pragma unroll
            for (int n2 = 0; n2 < 2; ++n2)
                bf[n2] = *(const f16x8*)&Bs[(wc + n2 * 32 + l31) * 64 + ((gq ^ (l31 & 7)) * 8)];
#pragma unroll
            for (int mr = 0; mr < 2; ++mr)
#pragma unroll
                for (int n2 = 0; n2 < 2; ++n2) acc[mr][n2] = MFMA32(af[mr], bf[n2], acc[mr][n2]);
        }
    }

    const int cc0 = col0 + wc + l31;
    const int cc1 = col0 + wc + 32 + l31;
    const int hh = (col0 + wc) >> 6;
#pragma unroll
    for (int mr = 0; mr < 2; ++mr)
#pragma unroll
        for (int j = 0; j < 16; ++j) {
            const int rr = row0 + wr + mr * 32 + (j & 3) + 8 * (j >> 2) + 4 * l5;
            if (F32OUT) {
                Cf[(size_t)rr * N + cc0] = acc[mr][0][j] + bias[cc0];
                Cf[(size_t)rr * N + cc1] = acc[mr][1][j] + bias[cc1];
            } else {
                const f16 h0 = (f16)(acc[mr][0][j] * osc);
                const f16 h1 = (f16)(acc[mr][1][j] * osc);
                if (NORMS) {
                    float v0 = (float)h0, v1 = (float)h1;
                    float s = v0 * v0 + v1 * v1;
                    s += __shfl_xor(s, 1);
                    s += __shfl_xor(s, 2);
                    s += __shfl_xor(s, 4);
                    s += __shfl_xor(s, 8);
                    s += __shfl_xor(s, 16);
                    if (l31 == 0)
                        nrmp[(size_t)((rr >> 10) * 16 + hh) * 1024 + (rr & 1023)] = s * nscale;
                }
                Cop[(size_t)rr * N + cc0] = h0;
                Cop[(size_t)rr * N + cc1] = h1;
            }
        }
}

// Fused qk + vT launch with XCD-aware mappings (dispatch round-robins bid%8):
//   qk (bid<512): z = bid&1 -> each XCD runs only q or k; per-XCD 64 tiles as
//     8 contiguous row-strips x all 8 col-strips (X 2MB + W 2MB = 4MB <= L2).
//   vT (bid>=512): per-XCD 4 token-col strips x all 8 Wv rows (3MB <= L2).
__global__ __launch_bounds__(256, 2) void gemm_qkv(const f16* __restrict__ X16,
                                                   const f16* __restrict__ W16,
                                                   f16* __restrict__ qb_base,
                                                   f16* __restrict__ vTb,
                                                   float* __restrict__ nrm,
                                                   float qsc, float ns_q, float ns_k) {
    __shared__ __attribute__((aligned(16))) f16 As[128 * 64];
    __shared__ __attribute__((aligned(16))) f16 Bs[128 * 64];
    const int bid = blockIdx.x;
    if (bid < 512) {
        const int z = bid & 1;
        const int t = (((bid & 7) >> 1) << 6) | (bid >> 3);  // bijective per z
        const int row0 = (t >> 3) * 128;  // 0..31 (8 contiguous strips per XCD)
        const int col0 = (t & 7) * 128;   // 0..7
        gemm128<true, false>(As, Bs,
                             X16 + (size_t)z * (4u << 20), W16 + (size_t)z * (1u << 20),
                             qb_base + (size_t)z * (4u << 20), nullptr, nullptr,
                             nrm + (size_t)z * 65536,
                             z ? 1.0f : qsc, z ? ns_k : ns_q, row0, col0, 1024, 1024);
    } else {
        const int f2 = bid - 512;
        const int x = f2 & 7, j = f2 >> 3;
        const int col0 = (x * 4 + (j & 3)) * 128;  // 4 token-strips per XCD
        const int row0 = (j >> 2) * 128;           // all 8 Wv row-strips
        gemm128<false, false>(As, Bs,
                              W16 + 2 * (1u << 20), X16 + 2 * (4u << 20),
                              vTb, nullptr, nullptr, nullptr,
                              1.0f, 0.f, row0, col0, 4096, 1024);
    }
}

// Final projection: 64x128 tiles, 512 blocks (2/CU). f32 out + bias.
__global__ __launch_bounds__(256, 2) void gemm_fin(const f16* __restrict__ A,
                                                   const f16* __restrict__ B,
                                                   float* __restrict__ Cf,
                                                   const float* __restrict__ bias) {
    __shared__ __attribute__((aligned(16))) f16 As[64 * 64];
    __shared__ __attribute__((aligned(16))) f16 Bs[128 * 64];
    const int tid = threadIdx.x;
    const int lane = tid & 63;
    const int w = tid >> 6;
    const int l31 = lane & 31, l5 = lane >> 5;
    const int wr = (w & 1) * 32, wc = (w >> 1) * 64;
    const int f = blockIdx.x;
    const int g = (f & 7) * 64 + (f >> 3);
    const int row0 = (g >> 3) * 64, col0 = (g & 7) * 128;
    const int K = 1024, N = 1024;

    f32x16 acc[2] = {};

    for (int kt = 0; kt < K; kt += 64) {
        __syncthreads();
#pragma unroll
        for (int t = 0; t < 2; ++t) {  // A: 64 rows
            const int rb = w * 16 + t * 8;
            const int rr = rb + (lane >> 3);
            const int gs = (lane & 7) ^ (rr & 7);
            stage16(&A[(size_t)(row0 + rr) * K + kt + gs * 8], &As[rb * 64]);
        }
#pragma unroll
        for (int t = 0; t < 4; ++t) {  // B: 128 rows
            const int rb = w * 32 + t * 8;
            const int rr = rb + (lane >> 3);
            const int gs = (lane & 7) ^ (rr & 7);
            stage16(&B[(size_t)(col0 + rr) * K + kt + gs * 8], &Bs[rb * 64]);
        }
        __syncthreads();
#pragma unroll
        for (int ks = 0; ks < 4; ++ks) {
            const int gq = ks * 2 + l5;
            f16x8 af = *(const f16x8*)&As[(wr + l31) * 64 + ((gq ^ (l31 & 7)) * 8)];
#pragma unroll
            for (int n2 = 0; n2 < 2; ++n2) {
                f16x8 bf = *(const f16x8*)&Bs[(wc + n2 * 32 + l31) * 64 + ((gq ^ (l31 & 7)) * 8)];
                acc[n2] = MFMA32(af, bf, acc[n2]);
            }
        }
    }

    const int cc0 = col0 + wc + l31;
    const int cc1 = col0 + wc + 32 + l31;
#pragma unroll
    for (int j = 0; j < 16; ++j) {
        const int rr = row0 + wr + (j & 3) + 8 * (j >> 2) + 4 * l5;
        Cf[(size_t)rr * N + cc0] = acc[0][j] + bias[cc0];
        Cf[(size_t)rr * N + cc1] = acc[1][j] + bias[cc1];
    }
}

// Distance attention: 1024 blocks x 256 threads, 64 q-rows/block (4 waves x 16),
// full-K loop. Swapped QK + permuted K slots => in-reg P; den via ones-MFMA.
// R14: K-frag ping-pong prefetch + V-frags hoisted above the trans chain.
__global__ __launch_bounds__(256, 2) void attn(const f16* __restrict__ qs,
                                               const f16* __restrict__ kb,
                                               const f16* __restrict__ vT,
                                               const float* __restrict__ q2c2,
                                               const float* __restrict__ k2c2,
                                               f16* __restrict__ out) {
    __shared__ __attribute__((aligned(16))) f16 Ks[128 * 64];  // permuted slots + XOR swizzle
    __shared__ __attribute__((aligned(16))) f16 Vs[64 * 128];  // XOR-swizzled
    __shared__ float k2tile[128];                              // linear (keyed by true k)
    const int tid = threadIdx.x;
    const int lane = tid & 63;
    const int w = tid >> 6;
    const int l15 = lane & 15, l4 = lane >> 4;
    const int fid = blockIdx.y * 16 + blockIdx.x;
    const int qt = (fid >> 3) & 15;
    const int bh = (fid & 7) * 8 + (fid >> 7);
    const int b = bh >> 4, h = bh & 15;
    const int wq = w * 16;
    const int hcol = h * 64;
    const int qrow0 = b * 1024 + qt * 64;
    const f16* vTh = vT + (size_t)hcol * 4096 + b * 1024;  // vT[d=1024][tok=4096]

    const int sr = tid >> 3, sc0 = (tid & 7) * 8;   // K staging (keys sr+i*32)
    const int vr = tid >> 4, vc0 = (tid & 15) * 8;  // V staging (rows vr+j*16)
    const int vsw = (vr & 7) << 3;
    const int fsw = (l15 & 7) << 3;                 // fragment-read swizzle

    f16x8 bq[2];
#pragma unroll
    for (int ks = 0; ks < 2; ++ks)
        bq[ks] = *(const f16x8*)&qs[(size_t)(qrow0 + wq + l15) * 1024 + hcol + ks * 32 + l4 * 8];
    const float q2m = q2c2[(size_t)bh * 1024 + qt * 64 + wq + l15];

    f32x4 accv[4] = {};
    f32x4 dacc = {};
    const f16 one = (f16)1.f;
    const f16x8 ones8 = {one, one, one, one, one, one, one, one};

    f16x8 kreg[4], vreg[4];
    float k2reg = 0.f;
#define ISSUE_LOADS(KT)                                                                                      \
    {                                                                                                        \
        _Pragma("unroll") for (int i = 0; i < 4; ++i)                                                        \
            kreg[i] = *(const f16x8*)&kb[(size_t)(b * 1024 + (KT) * 128 + sr + i * 32) * 1024 + hcol + sc0]; \
        _Pragma("unroll") for (int j = 0; j < 4; ++j)                                                        \
            vreg[j] = *(const f16x8*)&vTh[(size_t)(vr + j * 16) * 4096 + (KT) * 128 + vc0];                  \
        k2reg = (tid < 128) ? k2c2[(size_t)bh * 1024 + (KT) * 128 + tid] : 0.f;                              \
    }

    ISSUE_LOADS(0)

    for (int kt = 0; kt < 8; ++kt) {
        __syncthreads();
#pragma unroll
        for (int i = 0; i < 4; ++i) {
            const int kap = sr + i * 32;
            const int s = ((kap >> 5) & 3) * 32 + ((kap >> 2) & 1) * 16 + ((kap >> 3) & 3) * 4 + (kap & 3);
            *(f16x8*)&Ks[s * 64 + (sc0 ^ ((s & 7) << 3))] = kreg[i];
        }
#pragma unroll
        for (int j = 0; j < 4; ++j) *(f16x8*)&Vs[(vr + j * 16) * 128 + (vc0 ^ vsw)] = vreg[j];
        if (tid < 128) k2tile[tid] = k2reg;
        __syncthreads();
        if (kt < 7) ISSUE_LOADS(kt + 1)  // global prefetch hides under compute

        // K-frag ping-pong: preload kk=0's two windows
        f16x8 kfb[2][4];
#pragma unroll
        for (int hh = 0; hh < 2; ++hh) {
            kfb[0][hh * 2] = *(const f16x8*)&Ks[(hh * 16 + l15) * 64 + ((l4 * 8) ^ fsw)];
            kfb[0][hh * 2 + 1] = *(const f16x8*)&Ks[(hh * 16 + l15) * 64 + ((32 + l4 * 8) ^ fsw)];
        }
#pragma unroll
        for (int kk = 0; kk < 4; ++kk) {
            const int cb = kk & 1;
            if (kk < 3) {  // prefetch next window-pair's K frags
#pragma unroll
                for (int hh = 0; hh < 2; ++hh) {
                    const int n_ = (kk + 1) * 2 + hh;
                    kfb[cb ^ 1][hh * 2] = *(const f16x8*)&Ks[(n_ * 16 + l15) * 64 + ((l4 * 8) ^ fsw)];
                    kfb[cb ^ 1][hh * 2 + 1] = *(const f16x8*)&Ks[(n_ * 16 + l15) * 64 + ((32 + l4 * 8) ^ fsw)];
                }
            }
            // V frags issued BEFORE the trans chain (latency hides under it)
            f16x8 vf[4];
#pragma unroll
            for (int n2 = 0; n2 < 4; ++n2)
                vf[n2] = *(const f16x8*)&Vs[(n2 * 16 + l15) * 128 + ((kk * 32 + l4 * 8) ^ fsw)];

            unsigned um[4];
#pragma unroll
            for (int half = 0; half < 2; ++half) {
                f32x4 k2q = *(const f32x4*)&k2tile[kk * 32 + l4 * 8 + half * 4];
                f32x4 c0;
#pragma unroll
                for (int r = 0; r < 4; ++r) c0[r] = q2m + k2q[r];
                f32x4 st = MFMA16(kfb[cb][half * 2], bq[0], c0);
                st = MFMA16(kfb[cb][half * 2 + 1], bq[1], st);
                float p0 = EXP2F(SQRTF(fmaxf(st[0], 0.f)));
                float p1 = EXP2F(SQRTF(fmaxf(st[1], 0.f)));
                float p2 = EXP2F(SQRTF(fmaxf(st[2], 0.f)));
                float p3 = EXP2F(SQRTF(fmaxf(st[3], 0.f)));
                f16x2 lo = {(f16)p0, (f16)p1};
                f16x2 hi = {(f16)p2, (f16)p3};
                um[half * 2] = __builtin_bit_cast(unsigned, lo);
                um[half * 2 + 1] = __builtin_bit_cast(unsigned, hi);
            }
            uint4 u = {um[0], um[1], um[2], um[3]};
            f16x8 ap = __builtin_bit_cast(f16x8, u);
            dacc = MFMA16(ap, ones8, dacc);
#pragma unroll
            for (int n2 = 0; n2 < 4; ++n2) accv[n2] = MFMA16(ap, vf[n2], accv[n2]);
        }
    }

#pragma unroll
    for (int r = 0; r < 4; ++r) {
        const float rd = 1.0f / dacc[r];
#pragma unroll
        for (int n2 = 0; n2 < 4; ++n2)
            out[(size_t)(qrow0 + wq + l4 * 4 + r) * 1024 + hcol + n2 * 16 + l15] =
                (f16)(accv[n2][r] * rd);
    }
}

extern "C" void kernel_launch(void* const* d_in, const int* in_sizes, int n_in,
                              void* d_out, int out_size, void* d_ws, size_t ws_size,
                              hipStream_t stream) {
    const float* Xq = (const float*)d_in[0];
    const float* Xk = (const float*)d_in[1];
    const float* Xv = (const float*)d_in[2];
    const float* Wq = (const float*)d_in[3];
    const float* Wk = (const float*)d_in[4];
    const float* Wv = (const float*)d_in[5];
    const float* Wp = (const float*)d_in[6];
    const float* bp = (const float*)d_in[7];
    float* out = (float*)d_out;

    char* ws = (char*)d_ws;
    f16* W16 = (f16*)(ws);                      // 4M f16
    f16* X16 = (f16*)(ws + (8ull << 20));       // Xq16|Xk16|Xv16
    f16* qb = (f16*)(ws + (32ull << 20));       // qk out base (z-stride 4M f16)
    f16* kb = (f16*)(ws + (40ull << 20));
    f16* vTb = (f16*)(ws + (48ull << 20));
    f16* attnout = (f16*)(ws + (56ull << 20));
    (void)kb;
    // norms scratch in d_out head; written each launch before use, overwritten by final GEMM
    float* q2c2 = out;
    float* k2c2 = out + 65536;

    const float qsc = (float)(-2.0 * C2d);
    const float ns_q = (float)(1.0 / (4.0 * C2d));
    const float ns_k = (float)C2d;

    cvt_all<<<8192, 256, 0, stream>>>(Xq, Xk, Xv, Wq, Wk, Wv, Wp, W16, X16);

    // fused q-proj + k-proj + vT (768 blocks)
    gemm_qkv<<<768, 256, 0, stream>>>(X16, W16, qb, vTb, q2c2, qsc, ns_q, ns_k);

    attn<<<dim3(16, 64), 256, 0, stream>>>(qb, kb, vTb, q2c2, k2c2, attnout);

    gemm_fin<<<512, 256, 0, stream>>>(attnout, W16 + 3 * (1u << 20), out, bp);
}